// Round 9
// baseline (995.106 us; speedup 1.0000x reference)
//
#include <hip/hip_runtime.h>
#include <cstdint>
#include <cstddef>

#define NG 512        // NUM_GRAPHS
#define NN 131072     // N_NODES
#define NE 4194304    // N_EDGES
#define FIN 54        // F_IN
#define HG 16         // H_GCN
#define HL 32         // H_LSTM
#define NC 192        // N_CLASSES
#define TS 1024       // MAX_SEQ_LEN

#define NB 256        // dst buckets (dst>>9), 512 nodes each
#define WH 512        // histogram/scatter workgroups, 8192 edges each
#define EPW (NE/WH)   // 8192

__device__ __forceinline__ float rcpf(float x){ return __builtin_amdgcn_rcpf(x); }
__device__ __forceinline__ float sigf(float x){ return rcpf(1.0f + __expf(-x)); }
__device__ __forceinline__ float tanhfast(float x){ return 1.0f - 2.0f*rcpf(__expf(2.0f*x) + 1.0f); }

// Wave-uniform row load kept in the VECTOR (vmcnt) domain.
__device__ __forceinline__ float4 uload4(const float* p){
  unsigned long long a = (unsigned long long)p;
  asm volatile("" : "+v"(a));
  return *(const float4*)a;
}

#define CEPS 1e-6f
#define HEPS 1e-6f

// ---------------- counts = 0 ----------------
__global__ void k_initc(int* __restrict__ counts){
  counts[threadIdx.x] = 0;
}

// ---------------- per-graph node counts ----------------
__global__ void k_cnt(const int* __restrict__ batch, int* __restrict__ counts){
  int i = blockIdx.x*256 + threadIdx.x;
  if (i < NN) atomicAdd(&counts[batch[i]], 1);
}

// ---------------- exclusive scan of counts -> starts (1 block, 512 thr) ----------------
__global__ void k_scan(const int* __restrict__ counts, int* __restrict__ starts){
  __shared__ int sc[NG];
  int t = threadIdx.x;
  sc[t] = counts[t]; __syncthreads();
  for (int off = 1; off < NG; off <<= 1){
    int v = (t >= off) ? sc[t-off] : 0;
    __syncthreads();
    sc[t] += v;
    __syncthreads();
  }
  starts[t] = sc[t] - counts[t];
}

// ---------------- bucket histogram: hist[b*WH + w] ----------------
__global__ void k_hist(const int* __restrict__ ei, int* __restrict__ hist){
  int w = blockIdx.x, tid = threadIdx.x;
  __shared__ int h[NB];
  h[tid] = 0;
  __syncthreads();
  int e0 = w*EPW;
  for (int i = tid; i < EPW; i += 256) atomicAdd(&h[ei[NE + e0 + i] >> 9], 1);
  __syncthreads();
  hist[tid*WH + w] = h[tid];
}

// ---------------- scan 131072-entry histogram (1 block, 1024 thr) ----------------
__global__ void k_scanH(const int* __restrict__ hist, int* __restrict__ offs,
                        int* __restrict__ bstart){
  __shared__ int tot[1024];
  int t = threadIdx.x;
  int base = t*128;
  int s = 0;
  for (int i = 0; i < 128; i++) s += hist[base + i];
  tot[t] = s; __syncthreads();
  for (int o = 1; o < 1024; o <<= 1){
    int v = (t >= o) ? tot[t-o] : 0;
    __syncthreads();
    tot[t] += v;
    __syncthreads();
  }
  int run = tot[t] - s;
  for (int i = 0; i < 128; i++){
    int idx = base + i;
    int h = hist[idx];
    offs[idx] = run;
    if ((idx & (WH-1)) == 0) bstart[idx / WH] = run;
    run += h;
  }
  if (t == 0) bstart[NB] = NE;
}

// ---------------- bin pass B: scatter (src, dst&511) into bucket-sorted pairs ----------------
__global__ void k_binB(const int* __restrict__ ei, const int* __restrict__ offs,
                       uint2* __restrict__ pair){
  int w = blockIdx.x, tid = threadIdx.x;
  __shared__ int cur[NB];
  cur[tid] = offs[tid*WH + w];
  __syncthreads();
  int e0 = w*EPW;
  for (int i = tid; i < EPW; i += 256){
    int e = e0 + i;
    int s = ei[e], d = ei[NE + e];
    int b = d >> 9;
    int pos = atomicAdd(&cur[b], 1);
    pair[pos] = make_uint2((unsigned)s, (unsigned)(d & 511));
  }
}

// ---------------- bin pass C: per-bucket CSR finalize (one wg per bucket) ----------------
__global__ void k_binC(const uint2* __restrict__ pair, const int* __restrict__ bstart,
                       int* __restrict__ eoff, int* __restrict__ ecnt, int* __restrict__ csr){
  int b = blockIdx.x, tid = threadIdx.x;
  __shared__ int h2[512];
  __shared__ int cur[512];
  h2[tid] = 0; h2[tid + 256] = 0;
  __syncthreads();
  int e0 = bstart[b], e1 = bstart[b+1];
  for (int i = e0 + tid; i < e1; i += 256) atomicAdd(&h2[pair[i].y], 1);
  __syncthreads();
  cur[tid] = h2[tid]; cur[tid + 256] = h2[tid + 256];
  __syncthreads();
  for (int o = 1; o < 256; o <<= 1){
    int v0 = (tid >= o) ? cur[tid - o] : 0;
    int v1 = (tid >= o) ? cur[256 + tid - o] : 0;
    __syncthreads();
    cur[tid] += v0; cur[256 + tid] += v1;
    __syncthreads();
  }
  int half0 = cur[255];
  __syncthreads();
  cur[256 + tid] += half0;
  __syncthreads();
  int n0 = tid, n1 = tid + 256;
  int ex0 = cur[n0] - h2[n0];
  int ex1 = cur[n1] - h2[n1];
  eoff[b*512 + n0] = e0 + ex0; ecnt[b*512 + n0] = h2[n0];
  eoff[b*512 + n1] = e0 + ex1; ecnt[b*512 + n1] = h2[n1];
  __syncthreads();
  cur[n0] = e0 + ex0; cur[n1] = e0 + ex1;
  __syncthreads();
  for (int i = e0 + tid; i < e1; i += 256){
    uint2 u = pair[i];
    int pos = atomicAdd(&cur[u.y], 1);
    csr[pos] = (int)u.x;
  }
}

__global__ void k_dinv(const int* __restrict__ ecnt, float* __restrict__ dinv){
  int i = blockIdx.x*256 + threadIdx.x;
  if (i < NN) dinv[i] = 1.0f / sqrtf((float)(ecnt[i] + 1));  // deg = indeg + self-loop >= 1
}

// ---------------- xa = x @ w1 : stage x rows via LDS ----------------
__global__ void k_lin1(const float* __restrict__ x, const float* __restrict__ w1,
                       float* __restrict__ xa){
  __shared__ float w[FIN*HG];       // 864
  __shared__ float xs[16][FIN+2];   // pad to 56
  int tid = threadIdx.x;
  for (int i = tid; i < FIN*HG; i += 256) w[i] = w1[i];
  const float4* gx = (const float4*)(x + (size_t)blockIdx.x*16*FIN);
  if (tid < 216){
    float4 v4 = gx[tid];
    int fi = tid*4;
#pragma unroll
    for (int e = 0; e < 4; e++){
      int idx = fi + e;
      xs[idx/FIN][idx%FIN] = ((const float*)&v4)[e];
    }
  }
  __syncthreads();
  int node = tid >> 4, f = tid & 15;
  const float* xr = xs[node];
  float acc = 0.0f;
#pragma unroll
  for (int k = 0; k < FIN; k++) acc = fmaf(xr[k], w[k*HG + f], acc);
  xa[((size_t)blockIdx.x*16 + node)*HG + f] = acc;
}

// ---------------- gather conv (no atomics): 16 lanes per dst node ----------------
__global__ void k_gather(const float* __restrict__ v, const int* __restrict__ csr,
                         const int* __restrict__ eoff, const int* __restrict__ ecnt,
                         const float* __restrict__ dinv, const float* __restrict__ bias,
                         int dorelu, float* __restrict__ out){
  int gid = blockIdx.x*16 + (threadIdx.x >> 4);
  int f = threadIdx.x & 15;
  float dv = dinv[gid];
  float a0 = v[(size_t)gid*HG + f] * dv, a1 = 0.0f, a2 = 0.0f, a3 = 0.0f;
  int o = eoff[gid], n = ecnt[gid];
  int i = 0;
  for (; i + 8 <= n; i += 8){
    int s0 = csr[o+i],   s1 = csr[o+i+1], s2 = csr[o+i+2], s3 = csr[o+i+3];
    int s4 = csr[o+i+4], s5 = csr[o+i+5], s6 = csr[o+i+6], s7 = csr[o+i+7];
    a0 = fmaf(v[(size_t)s0*HG + f], dinv[s0], a0);
    a1 = fmaf(v[(size_t)s1*HG + f], dinv[s1], a1);
    a2 = fmaf(v[(size_t)s2*HG + f], dinv[s2], a2);
    a3 = fmaf(v[(size_t)s3*HG + f], dinv[s3], a3);
    a0 = fmaf(v[(size_t)s4*HG + f], dinv[s4], a0);
    a1 = fmaf(v[(size_t)s5*HG + f], dinv[s5], a1);
    a2 = fmaf(v[(size_t)s6*HG + f], dinv[s6], a2);
    a3 = fmaf(v[(size_t)s7*HG + f], dinv[s7], a3);
  }
  for (; i + 4 <= n; i += 4){
    int s0 = csr[o+i], s1 = csr[o+i+1], s2 = csr[o+i+2], s3 = csr[o+i+3];
    a0 = fmaf(v[(size_t)s0*HG + f], dinv[s0], a0);
    a1 = fmaf(v[(size_t)s1*HG + f], dinv[s1], a1);
    a2 = fmaf(v[(size_t)s2*HG + f], dinv[s2], a2);
    a3 = fmaf(v[(size_t)s3*HG + f], dinv[s3], a3);
  }
  for (; i < n; i++){
    int s = csr[o+i];
    a0 = fmaf(v[(size_t)s*HG + f], dinv[s], a0);
  }
  float acc = ((a0 + a1) + (a2 + a3)) * dv;
  if (dorelu) acc = fmaxf(acc + bias[f], 0.0f);
  out[(size_t)gid*HG + f] = acc;
}

// ---------------- hb = relu(agg + b1) @ w2 ----------------
__global__ void k_relu_lin(const float* __restrict__ agg, const float* __restrict__ b1,
                           const float* __restrict__ w2, float* __restrict__ hb){
  __shared__ float w[HG*HG];
  __shared__ float bb[HG];
  int tid = threadIdx.x;
  if (tid < HG*HG) w[tid] = w2[tid];
  if (tid < HG) bb[tid] = b1[tid];
  __syncthreads();
  int id = blockIdx.x*256 + tid;
  if (id >= NN*HG) return;
  int node = id >> 4, f = id & 15;
  const float* ar = agg + (size_t)node*HG;
  float acc = 0.0f;
#pragma unroll
  for (int k = 0; k < HG; k++){
    float h = fmaxf(ar[k] + bb[k], 0.0f);
    acc = fmaf(h, w[k*HG + f], acc);
  }
  hb[id] = acc;
}

// ============ BiLSTM ============
// Fact established R2-R8: step time ~1700cy is ISSUE-INDEPENDENT (lstm0 ~160
// inst/step == lstm1 ~350 inst/step in time; R8 pipelining null). The floor is
// the loop-carried chain. R9: lstm1 becomes producer/consumer (2 waves): the
// producer computes x-projection quads (bitwise-identical a0..a3/b0..b3
// accumulators) into a 16-slot LDS ring; the consumer's chain is only
// quad-read -> h-FMA -> tail -> h. lstm0 unchanged (control).

// two-exchange tail (lstm0, R5-proven)
#define LTAIL() \
  float uA = (a0 + a1) + (a2 + a3); \
  float uB = (b0 + b1) + (b2 + b3); \
  float aA = sigf(uA); \
  float ub2 = half ? uB : (uB + uB); \
  float sv = sigf(ub2); \
  float aB = half ? sv : (sv + sv - 1.0f); \
  float pq = aA*aB; \
  float part = __shfl_xor(half ? aA : pq, 32); \
  float f_ = half ? aA : part; \
  float p_ = half ? part : pq; \
  float cn = fmaf(f_, c, p_); \
  float th = tanhfast(cn); \
  float ov = __shfl_xor(aB, 32); \
  float o_ = half ? aB : ov; \
  float hn = o_ * th;

// ---------------- layer 0 (R5 version, control) ----------------
__global__ __launch_bounds__(64, 1) void k_lstm0(
    const float* __restrict__ h2in, const int* __restrict__ starts, const int* __restrict__ counts,
    const float* __restrict__ wih, const float* __restrict__ whh,
    const float* __restrict__ bih, const float* __restrict__ bhh,
    float* __restrict__ out0, int* __restrict__ tconv, int* __restrict__ az)
{
  const int g = blockIdx.x >> 1, dir = blockIdx.x & 1;
  const int lane = threadIdx.x;            // 0..63
  const int j = lane & 31, half = lane >> 5;
  const int rA = (half ? 32 : 0) + j;      // i_j (half0) or f_j (half1)
  const int rB = rA + 64;                  // g_j (half0) or o_j (half1)
  float wxA[HG], wxB[HG], whA[HL], whB[HL];
  { const float4* a4 = (const float4*)(wih + ((size_t)dir*128 + rA)*HG);
    const float4* b4 = (const float4*)(wih + ((size_t)dir*128 + rB)*HG);
#pragma unroll
    for (int k = 0; k < HG/4; k++){ ((float4*)wxA)[k] = a4[k]; ((float4*)wxB)[k] = b4[k]; }
    const float4* ua4 = (const float4*)(whh + ((size_t)dir*128 + rA)*HL);
    const float4* ub4 = (const float4*)(whh + ((size_t)dir*128 + rB)*HL);
#pragma unroll
    for (int k = 0; k < HL/4; k++){ ((float4*)whA)[k] = ua4[k]; ((float4*)whB)[k] = ub4[k]; }
  }
  const float pbA = bih[dir*128 + rA] + bhh[dir*128 + rA];
  const float pbB = bih[dir*128 + rB] + bhh[dir*128 + rB];
  int cnt = counts[g]; if (cnt > TS) cnt = TS;
  const int s0 = starts[g];
  float* outg = out0 + (size_t)g*TS*64 + dir*32;

  __shared__ __align__(16) float hbuf[HL];

  unsigned long long bz = __ballot((pbA == 0.0f) && (pbB == 0.0f));
  bool allzero = (bz == ~0ull);
  if (dir == 1 && lane == 0) az[0] = allzero ? 1 : 0;
  if (!half) hbuf[j] = 0.0f;
  float4 H[8];
  { const float4* h4r = (const float4*)hbuf;
#pragma unroll
    for (int q = 0; q < 8; q++) H[q] = h4r[q]; }

  float c = 0.0f, h = 0.0f;
  int t, dt, tendF;

#define L0_HFMA() \
  _Pragma("unroll") \
  for (int q = 0; q < 8; q++){ float4 hq = H[q]; \
    a0 = fmaf(hq.x, whA[4*q+0], a0); a1 = fmaf(hq.y, whA[4*q+1], a1); \
    a2 = fmaf(hq.z, whA[4*q+2], a2); a3 = fmaf(hq.w, whA[4*q+3], a3); \
    b0 = fmaf(hq.x, whB[4*q+0], b0); b1 = fmaf(hq.y, whB[4*q+1], b1); \
    b2 = fmaf(hq.z, whB[4*q+2], b2); b3 = fmaf(hq.w, whB[4*q+3], b3); }

#define L0_STORE() \
  c = cn; h = hn; \
  if (!half) hbuf[j] = h; \
  { const float4* h4r = (const float4*)hbuf; \
    _Pragma("unroll") for (int q = 0; q < 8; q++) H[q] = h4r[q]; } \
  if (half) outg[(size_t)t*64 + j] = h;

#define L0_F(P) { \
  if (t == tendF) goto l0_fdone; \
  float a0 = pbA, a1 = 0.0f, a2 = 0.0f, a3 = 0.0f; \
  float b0 = pbB, b1 = 0.0f, b2 = 0.0f, b3 = 0.0f; \
  _Pragma("unroll") \
  for (int q = 0; q < 4; q++){ float4 xq = XR##P[q]; \
    a0 = fmaf(xq.x, wxA[4*q+0], a0); a1 = fmaf(xq.y, wxA[4*q+1], a1); \
    a2 = fmaf(xq.z, wxA[4*q+2], a2); a3 = fmaf(xq.w, wxA[4*q+3], a3); \
    b0 = fmaf(xq.x, wxB[4*q+0], b0); b1 = fmaf(xq.y, wxB[4*q+1], b1); \
    b2 = fmaf(xq.z, wxB[4*q+2], b2); b3 = fmaf(xq.w, wxB[4*q+3], b3); } \
  { int tp = t + 4*dt; tp = tp < 0 ? 0 : (tp > cnt-1 ? cnt-1 : tp); \
    const float* pp = h2in + (size_t)(s0 + tp)*HG; \
    XR##P[0] = uload4(pp); XR##P[1] = uload4(pp+4); \
    XR##P[2] = uload4(pp+8); XR##P[3] = uload4(pp+12); } \
  L0_HFMA(); \
  LTAIL(); \
  L0_STORE(); \
  t += dt; }

  // dir1 non-az pre-phase: zero-input descending steps TS-1 .. cnt
  if (dir == 1 && !allzero){
    for (t = TS - 1; t >= cnt; t--){
      float a0 = pbA, a1 = 0.0f, a2 = 0.0f, a3 = 0.0f;
      float b0 = pbB, b1 = 0.0f, b2 = 0.0f, b3 = 0.0f;
      L0_HFMA();
      LTAIL();
      L0_STORE();
    }
  }

  // full phase over real rows, 4-deep rolling register prefetch
  if (cnt > 0){
    if (dir == 0){ t = 0; dt = 1; tendF = cnt; }
    else { t = cnt - 1; dt = -1; tendF = -1; }
    if (!(dir == 1 && t < 0)){
      float4 XR0[4], XR1[4], XR2[4], XR3[4];
      { int r1 = t + dt, r2 = t + 2*dt, r3 = t + 3*dt;
        r1 = r1 < 0 ? 0 : (r1 > cnt-1 ? cnt-1 : r1);
        r2 = r2 < 0 ? 0 : (r2 > cnt-1 ? cnt-1 : r2);
        r3 = r3 < 0 ? 0 : (r3 > cnt-1 ? cnt-1 : r3);
        const float* p0 = h2in + (size_t)(s0 + t)*HG;
        const float* p1 = h2in + (size_t)(s0 + r1)*HG;
        const float* p2 = h2in + (size_t)(s0 + r2)*HG;
        const float* p3 = h2in + (size_t)(s0 + r3)*HG;
        XR0[0]=uload4(p0); XR0[1]=uload4(p0+4); XR0[2]=uload4(p0+8); XR0[3]=uload4(p0+12);
        XR1[0]=uload4(p1); XR1[1]=uload4(p1+4); XR1[2]=uload4(p1+8); XR1[3]=uload4(p1+12);
        XR2[0]=uload4(p2); XR2[1]=uload4(p2+4); XR2[2]=uload4(p2+8); XR2[3]=uload4(p2+12);
        XR3[0]=uload4(p3); XR3[1]=uload4(p3+4); XR3[2]=uload4(p3+8); XR3[3]=uload4(p3+12);
      }
      for (;;){ L0_F(0); L0_F(1); L0_F(2); L0_F(3); }
l0_fdone: ;
    }
  }

  // dir0 zero-input tail with convergence detection
  if (dir == 0){
    bool fwdconv = false;
    for (t = cnt; t < TS; t++){
      float a0 = pbA, a1 = 0.0f, a2 = 0.0f, a3 = 0.0f;
      float b0 = pbB, b1 = 0.0f, b2 = 0.0f, b3 = 0.0f;
      L0_HFMA();
      LTAIL();
      bool eq = (fabsf(cn - c) <= CEPS*(1.0f + fabsf(cn))) && (fabsf(hn - h) <= HEPS);
      L0_STORE();
      unsigned long long m = __ballot(eq);
      if (t >= cnt + 1 && m == ~0ull){
        if (lane == 0) tconv[g] = t - 1;
        fwdconv = true;
        break;
      }
    }
    if (!fwdconv && lane == 0) tconv[g] = TS;
  }
#undef L0_F
#undef L0_STORE
#undef L0_HFMA
}

// ---------------- layer 1 + mean pool: producer/consumer, 2 waves ----------------
// wave0 (producer): per row r, computes the x-projection quads
// {a0..a3 of gate rA, b0..b3 of gate rB} with the EXACT accumulation order of
// the R8 GATES8 macro (bitwise identical), writes them SoA into a 16-slot LDS
// ring (slot = r & 15), then sets flag[slot] = r after lgkmcnt(0).
// wave1 (consumer): spins on flag, reads 8 quad components (conflict-free
// b32), h-FMAs + single-exchange tail (R8-proven), publishes consume count.
// Flow control: producer waits n >= k-15 before writing its k-th row.
__global__ __launch_bounds__(128, 1) void k_lstm1(
    const float* __restrict__ gl0, const int* __restrict__ tconv,
    const int* __restrict__ counts, const int* __restrict__ az,
    const float* __restrict__ wih, const float* __restrict__ whh,
    const float* __restrict__ bih, const float* __restrict__ bhh,
    float* __restrict__ pooled)
{
  const int g = blockIdx.x >> 1, dir = blockIdx.x & 1;
  const int tid = threadIdx.x;
  const int wid = tid >> 6;          // 0 = producer, 1 = consumer
  const int lane = tid & 63;
  const int j = lane & 31, half = lane >> 5;
  const int rA = (half ? 32 : 0) + j, rB = rA + 64;

  const float* gin = gl0 + (size_t)g*TS*64;
  const int tcv = tconv[g];
  int cnt = counts[g]; if (cnt > TS) cnt = TS;
  const bool spec = (tcv + 1 <= TS - 1);   // cheap/constant row tcv+1 exists
  const int K = spec ? (tcv + 2) : TS;     // rows produced (both dirs)

  __shared__ __align__(16) float ring[8*16*64];  // [comp][slot][lane], 32 KB
  __shared__ int fl[16];
  __shared__ int nsh;
  __shared__ __align__(16) float xrow[2][64];
  __shared__ __align__(16) float hbuf[HL];

  if (tid < 16) fl[tid] = -1;
  if (tid == 16) nsh = 0;
  if (wid == 1 && !half) hbuf[j] = 0.0f;
  __syncthreads();

  volatile int* nv = (volatile int*)&nsh;

  if (wid == 0){
    // =================== PRODUCER ===================
    const bool mzp = (az[0] != 0) && (half != 0);  // zero hi columns of rows >= cnt
    float wxA[64], wxB[64];
    { const float4* A4 = (const float4*)(wih + ((size_t)dir*128 + rA)*64);
      const float4* B4 = (const float4*)(wih + ((size_t)dir*128 + rB)*64);
#pragma unroll
      for (int k = 0; k < 16; k++){ ((float4*)wxA)[k] = A4[k]; ((float4*)wxB)[k] = B4[k]; }
    }
    const float pbA = bih[dir*128 + rA] + bhh[dir*128 + rA];
    const float pbB = bih[dir*128 + rB] + bhh[dir*128 + rB];

#define P_ROW(KK) (dir == 0 ? (KK) : (spec ? ((KK) == 0 ? tcv+1 : tcv+1-(KK)) : TS-1-(KK)))
#define P_ROWCL(KK) P_ROW((KK) < 0 ? 0 : ((KK) > K-1 ? K-1 : (KK)))

    { int r0 = P_ROW(0);
      float xv = gin[(size_t)r0*64 + lane];
      if (mzp && r0 >= cnt) xv = 0.0f;
      xrow[0][lane] = xv; }
    float v1 = gin[(size_t)P_ROWCL(1)*64 + lane];
    float v2 = gin[(size_t)P_ROWCL(2)*64 + lane];
    float v3 = gin[(size_t)P_ROWCL(3)*64 + lane];

    for (int k = 0; k < K; k++){
      int r = P_ROW(k);
      while (*nv < k - 15) __builtin_amdgcn_s_sleep(2);   // ring-full backoff
      float a0 = pbA, a1 = 0.0f, a2 = 0.0f, a3 = 0.0f;
      float b0 = pbB, b1 = 0.0f, b2 = 0.0f, b3 = 0.0f;
      { const float4* xp_ = (const float4*)xrow[k & 1];
#pragma unroll
        for (int q = 0; q < 16; q++){ float4 xq = xp_[q];
          a0 = fmaf(xq.x, wxA[4*q+0], a0); a1 = fmaf(xq.y, wxA[4*q+1], a1);
          a2 = fmaf(xq.z, wxA[4*q+2], a2); a3 = fmaf(xq.w, wxA[4*q+3], a3);
          b0 = fmaf(xq.x, wxB[4*q+0], b0); b1 = fmaf(xq.y, wxB[4*q+1], b1);
          b2 = fmaf(xq.z, wxB[4*q+2], b2); b3 = fmaf(xq.w, wxB[4*q+3], b3); } }
      if (k + 1 < K){
        int rn = P_ROW(k+1);
        float xw = (mzp && rn >= cnt) ? 0.0f : v1;
        xrow[(k+1) & 1][lane] = xw;
        v1 = v2; v2 = v3;
        v3 = gin[(size_t)P_ROWCL(k+4)*64 + lane];
      }
      int slot = r & 15;
      float* rp = ring + slot*64 + lane;
      rp[0]    = a0; rp[1024] = a1; rp[2048] = a2; rp[3072] = a3;
      rp[4096] = b0; rp[5120] = b1; rp[6144] = b2; rp[7168] = b3;
      asm volatile("s_waitcnt lgkmcnt(0)" ::: "memory");   // quads committed
      *(volatile int*)&fl[slot] = r;                        // publish
    }
#undef P_ROW
#undef P_ROWCL
  } else {
    // =================== CONSUMER ===================
    float whA[HL], whB[HL];
    { const float4* a4 = (const float4*)(whh + ((size_t)dir*128 + rA)*HL);
      const float4* b4 = (const float4*)(whh + ((size_t)dir*128 + rB)*HL);
#pragma unroll
      for (int k = 0; k < 8; k++){ ((float4*)whA)[k] = a4[k]; ((float4*)whB)[k] = b4[k]; }
    }
    float c = 0.0f, h = 0.0f, hsum = 0.0f;
    float xA0, xA1, xA2, xA3, xB0, xB1, xB2, xB3;
    int ncount = 0;

#define C_SPINREAD(T) { int t_ = (T), slot_ = t_ & 15; \
  volatile int* fp_ = (volatile int*)&fl[slot_]; \
  while (*fp_ != t_) {} \
  asm volatile("" ::: "memory"); \
  const float* rp_ = ring + slot_*64 + lane; \
  xA0 = rp_[0];    xA1 = rp_[1024]; xA2 = rp_[2048]; xA3 = rp_[3072]; \
  xB0 = rp_[4096]; xB1 = rp_[5120]; xB2 = rp_[6144]; xB3 = rp_[7168]; }

#define C_PUB() { ncount++; if (lane == 0) *nv = ncount; }

#define C_HFMA8(A0,A1,A2,A3,B0,B1,B2,B3) \
  { const float4* h4_ = (const float4*)hbuf; \
    _Pragma("unroll") \
    for (int q = 0; q < 8; q++){ float4 hq = h4_[q]; \
      A0 = fmaf(hq.x, whA[4*q+0], A0); A1 = fmaf(hq.y, whA[4*q+1], A1); \
      A2 = fmaf(hq.z, whA[4*q+2], A2); A3 = fmaf(hq.w, whA[4*q+3], A3); \
      B0 = fmaf(hq.x, whB[4*q+0], B0); B1 = fmaf(hq.y, whB[4*q+1], B1); \
      B2 = fmaf(hq.z, whB[4*q+2], B2); B3 = fmaf(hq.w, whB[4*q+3], B3); } }

#define C_STEP() { \
  float a0 = xA0, a1 = xA1, a2 = xA2, a3 = xA3; \
  float b0 = xB0, b1 = xB1, b2 = xB2, b3 = xB3; \
  C_HFMA8(a0,a1,a2,a3,b0,b1,b2,b3); \
  float uA = (a0 + a1) + (a2 + a3); \
  float uB = (b0 + b1) + (b2 + b3); \
  float actA = sigf(uA); \
  float ub2 = half ? uB : (uB + uB); \
  float sv = sigf(ub2); \
  float actB = half ? sv : (sv + sv - 1.0f); \
  float pq_ = actA*actB; \
  float part = __shfl_xor(half ? actA : pq_, 32); \
  float f_ = half ? actA : part; \
  float p_ = half ? part : pq_; \
  float cn = fmaf(f_, c, p_); \
  float th = tanhfast(cn); \
  c = cn; \
  if (half){ float hn = actB * th; h = hn; hbuf[j] = hn; hsum += hn; } }

#define C_CSTEP(EQ) \
  float a0 = xA0, a1 = xA1, a2 = xA2, a3 = xA3; \
  float b0 = xB0, b1 = xB1, b2 = xB2, b3 = xB3; \
  C_HFMA8(a0,a1,a2,a3,b0,b1,b2,b3); \
  float uA = (a0 + a1) + (a2 + a3); \
  float uB = (b0 + b1) + (b2 + b3); \
  float actA = sigf(uA); \
  float ub2 = half ? uB : (uB + uB); \
  float sv = sigf(ub2); \
  float actB = half ? sv : (sv + sv - 1.0f); \
  float pq_ = actA*actB; \
  float part = __shfl_xor(half ? actA : pq_, 32); \
  float f_ = half ? actA : part; \
  float p_ = half ? part : pq_; \
  float cn = fmaf(f_, c, p_); \
  float th = tanhfast(cn); \
  float hn = actB * th; \
  bool EQ = (fabsf(cn - c) <= CEPS*(1.0f + fabsf(cn))) && (!half || (fabsf(hn - h) <= HEPS)); \
  c = cn; \
  if (half){ h = hn; hbuf[j] = hn; hsum += hn; }

    if (dir == 0){
      const int tend = (tcv < TS-1) ? tcv : TS-1;
      for (int t = 0; t <= tend; t++){
        C_SPINREAD(t); C_STEP(); C_PUB();
      }
      if (spec){
        C_SPINREAD(tcv+1); C_PUB();           // constant-row quads -> registers
        for (int tt = tcv+1; tt < TS; tt++){
          C_CSTEP(eq);
          unsigned long long m = __ballot(eq);
          if (m == ~0ull){ hsum += h * (float)(TS-1 - tt); break; }  // fixed point
        }
      }
    } else {
      int tfull;
      if (spec){
        C_SPINREAD(tcv+1); C_PUB();           // constant-row quads first
        bool jumped = false;
        for (int tt = TS-1; tt >= tcv+1; tt--){
          C_CSTEP(eq);
          unsigned long long m = __ballot(eq);
          if (m == ~0ull){ hsum += h * (float)(tt - tcv); jumped = true; break; }
        }
        tfull = jumped ? (tcv - 1) : tcv;
      } else tfull = TS - 1;
      for (int t = tfull; t >= 0; t--){
        C_SPINREAD(t); C_STEP(); C_PUB();
      }
    }
    if (half) pooled[(size_t)g*64 + dir*32 + j] = hsum * (1.0f/(float)TS);
#undef C_SPINREAD
#undef C_PUB
#undef C_HFMA8
#undef C_STEP
#undef C_CSTEP
  }
}

// ---------------- FC: out = pooled @ fc_w + fc_b ----------------
__global__ void k_fc(const float* __restrict__ pooled, const float* __restrict__ fcw,
                     const float* __restrict__ fcb, float* __restrict__ out){
  __shared__ float p[64];
  int g = blockIdx.x, cix = threadIdx.x;
  if (cix < 64) p[cix] = pooled[(size_t)g*64 + cix];
  __syncthreads();
  float acc = fcb[cix];
#pragma unroll
  for (int k = 0; k < 64; k++) acc = fmaf(p[k], fcw[k*NC + cix], acc);
  out[(size_t)g*NC + cix] = acc;
}

extern "C" void kernel_launch(void* const* d_in, const int* in_sizes, int n_in,
                              void* d_out, int out_size, void* d_ws, size_t ws_size,
                              hipStream_t stream) {
  const float* x        = (const float*)d_in[0];
  const int*   ei       = (const int*)  d_in[1];
  const int*   batch    = (const int*)  d_in[2];
  const float* gcn_w1   = (const float*)d_in[3];
  const float* gcn_b1   = (const float*)d_in[4];
  const float* gcn_w2   = (const float*)d_in[5];
  const float* gcn_b2   = (const float*)d_in[6];
  const float* l0_wih   = (const float*)d_in[7];
  const float* l0_whh   = (const float*)d_in[8];
  const float* l0_bih   = (const float*)d_in[9];
  const float* l0_bhh   = (const float*)d_in[10];
  const float* l1_wih   = (const float*)d_in[11];
  const float* l1_whh   = (const float*)d_in[12];
  const float* l1_bih   = (const float*)d_in[13];
  const float* l1_bhh   = (const float*)d_in[14];
  const float* fc_w     = (const float*)d_in[15];
  const float* fc_b     = (const float*)d_in[16];
  float* out = (float*)d_out;

  // workspace layout (4B units)
  float* ws   = (float*)d_ws;
  float* B0   = ws;                        // NN*16
  float* B1   = B0 + (size_t)NN*HG;        // NN*16
  float* B2   = B1 + (size_t)NN*HG;        // NN*16
  float* dinv = B2 + (size_t)NN*HG;        // NN
  int*   ecnt   = (int*)(dinv + NN);       // NN
  int*   eoff   = ecnt + NN;               // NN
  int*   hist   = eoff + NN;               // NB*WH = 131072
  int*   offs   = hist + NB*WH;            // 131072
  int*   counts = offs + NB*WH;            // 512
  int*   starts = counts + NG;             // 512
  int*   tconv  = starts + NG;             // 512
  int*   bstart = tconv + NG;              // NB+1
  int*   az     = bstart + NB + 4;         // 1 (inside 64-int pad)
  float* pooled = (float*)(bstart + NB + 64);      // 512*64 (64-int pad)
  int*   csr    = (int*)(pooled + (size_t)NG*64);  // NE
  float* out0   = (float*)(csr + (size_t)NE);      // 512*1024*64
  uint2* pair   = (uint2*)out0;                    // NE*2 ints, aliases out0 (dead before lstm0)
  size_t needed = ((size_t)((float*)out0 - ws) + (size_t)NG*TS*64) * sizeof(float);
  if (ws_size < needed) return;  // fail loudly (poisoned d_out) rather than corrupt

  k_initc <<<1, NG, 0, stream>>>(counts);
  k_cnt   <<<NN/256, 256, 0, stream>>>(batch, counts);
  k_hist  <<<WH, 256, 0, stream>>>(ei, hist);
  k_scanH <<<1, 1024, 0, stream>>>(hist, offs, bstart);
  k_scan  <<<1, NG, 0, stream>>>(counts, starts);
  k_binB  <<<WH, 256, 0, stream>>>(ei, offs, pair);
  k_binC  <<<NB, 256, 0, stream>>>(pair, bstart, eoff, ecnt, csr);
  k_dinv  <<<NN/256, 256, 0, stream>>>(ecnt, dinv);
  k_lin1  <<<NN/16, 256, 0, stream>>>(x, gcn_w1, B0);
  k_gather<<<(NN*HG)/256, 256, 0, stream>>>(B0, csr, eoff, ecnt, dinv, gcn_b2, 0, B1);
  k_relu_lin<<<(NN*HG)/256, 256, 0, stream>>>(B1, gcn_b1, gcn_w2, B2);
  k_gather<<<(NN*HG)/256, 256, 0, stream>>>(B2, csr, eoff, ecnt, dinv, gcn_b2, 1, B1);
  k_lstm0 <<<NG*2, 64, 0, stream>>>(B1, starts, counts, l0_wih, l0_whh, l0_bih, l0_bhh, out0, tconv, az);
  k_lstm1 <<<NG*2, 128, 0, stream>>>(out0, tconv, counts, az, l1_wih, l1_whh, l1_bih, l1_bhh, pooled);
  k_fc    <<<NG, NC, 0, stream>>>(pooled, fc_w, fc_b, out);
}

// Round 10
// 961.214 us; speedup vs baseline: 1.0353x; 1.0353x over previous
//
#include <hip/hip_runtime.h>
#include <cstdint>
#include <cstddef>

#define NG 512        // NUM_GRAPHS
#define NN 131072     // N_NODES
#define NE 4194304    // N_EDGES
#define FIN 54        // F_IN
#define HG 16         // H_GCN
#define HL 32         // H_LSTM
#define NC 192        // N_CLASSES
#define TS 1024       // MAX_SEQ_LEN

#define NB 256        // dst buckets (dst>>9), 512 nodes each
#define WH 512        // histogram/scatter workgroups, 8192 edges each
#define EPW (NE/WH)   // 8192

__device__ __forceinline__ float rcpf(float x){ return __builtin_amdgcn_rcpf(x); }
__device__ __forceinline__ float sigf(float x){ return rcpf(1.0f + __expf(-x)); }
__device__ __forceinline__ float tanhfast(float x){ return 1.0f - 2.0f*rcpf(__expf(2.0f*x) + 1.0f); }

// Wave-uniform row load kept in the VECTOR (vmcnt) domain (s_load shares
// lgkmcnt with DS -> serializing waits in the LDS-heavy step).
__device__ __forceinline__ float4 uload4(const float* p){
  unsigned long long a = (unsigned long long)p;
  asm volatile("" : "+v"(a));
  return *(const float4*)a;
}

#define CEPS 1e-6f
#define HEPS 1e-6f

// ---------------- counts = 0 ----------------
__global__ void k_initc(int* __restrict__ counts){
  counts[threadIdx.x] = 0;
}

// ---------------- per-graph node counts ----------------
__global__ void k_cnt(const int* __restrict__ batch, int* __restrict__ counts){
  int i = blockIdx.x*256 + threadIdx.x;
  if (i < NN) atomicAdd(&counts[batch[i]], 1);
}

// ---------------- exclusive scan of counts -> starts (1 block, 512 thr) ----------------
__global__ void k_scan(const int* __restrict__ counts, int* __restrict__ starts){
  __shared__ int sc[NG];
  int t = threadIdx.x;
  sc[t] = counts[t]; __syncthreads();
  for (int off = 1; off < NG; off <<= 1){
    int v = (t >= off) ? sc[t-off] : 0;
    __syncthreads();
    sc[t] += v;
    __syncthreads();
  }
  starts[t] = sc[t] - counts[t];
}

// ---------------- bucket histogram: hist[b*WH + w] ----------------
__global__ void k_hist(const int* __restrict__ ei, int* __restrict__ hist){
  int w = blockIdx.x, tid = threadIdx.x;
  __shared__ int h[NB];
  h[tid] = 0;
  __syncthreads();
  int e0 = w*EPW;
  for (int i = tid; i < EPW; i += 256) atomicAdd(&h[ei[NE + e0 + i] >> 9], 1);
  __syncthreads();
  hist[tid*WH + w] = h[tid];
}

// ---------------- scan 131072-entry histogram (1 block, 1024 thr) ----------------
__global__ void k_scanH(const int* __restrict__ hist, int* __restrict__ offs,
                        int* __restrict__ bstart){
  __shared__ int tot[1024];
  int t = threadIdx.x;
  int base = t*128;
  int s = 0;
  for (int i = 0; i < 128; i++) s += hist[base + i];
  tot[t] = s; __syncthreads();
  for (int o = 1; o < 1024; o <<= 1){
    int v = (t >= o) ? tot[t-o] : 0;
    __syncthreads();
    tot[t] += v;
    __syncthreads();
  }
  int run = tot[t] - s;
  for (int i = 0; i < 128; i++){
    int idx = base + i;
    int h = hist[idx];
    offs[idx] = run;
    if ((idx & (WH-1)) == 0) bstart[idx / WH] = run;
    run += h;
  }
  if (t == 0) bstart[NB] = NE;
}

// ---------------- bin pass B: scatter (src, dst&511) into bucket-sorted pairs ----------------
__global__ void k_binB(const int* __restrict__ ei, const int* __restrict__ offs,
                       uint2* __restrict__ pair){
  int w = blockIdx.x, tid = threadIdx.x;
  __shared__ int cur[NB];
  cur[tid] = offs[tid*WH + w];
  __syncthreads();
  int e0 = w*EPW;
  for (int i = tid; i < EPW; i += 256){
    int e = e0 + i;
    int s = ei[e], d = ei[NE + e];
    int b = d >> 9;
    int pos = atomicAdd(&cur[b], 1);
    pair[pos] = make_uint2((unsigned)s, (unsigned)(d & 511));
  }
}

// ---------------- bin pass C: per-bucket CSR finalize (one wg per bucket) ----------------
__global__ void k_binC(const uint2* __restrict__ pair, const int* __restrict__ bstart,
                       int* __restrict__ eoff, int* __restrict__ ecnt, int* __restrict__ csr){
  int b = blockIdx.x, tid = threadIdx.x;
  __shared__ int h2[512];
  __shared__ int cur[512];
  h2[tid] = 0; h2[tid + 256] = 0;
  __syncthreads();
  int e0 = bstart[b], e1 = bstart[b+1];
  for (int i = e0 + tid; i < e1; i += 256) atomicAdd(&h2[pair[i].y], 1);
  __syncthreads();
  cur[tid] = h2[tid]; cur[tid + 256] = h2[tid + 256];
  __syncthreads();
  for (int o = 1; o < 256; o <<= 1){
    int v0 = (tid >= o) ? cur[tid - o] : 0;
    int v1 = (tid >= o) ? cur[256 + tid - o] : 0;
    __syncthreads();
    cur[tid] += v0; cur[256 + tid] += v1;
    __syncthreads();
  }
  int half0 = cur[255];
  __syncthreads();
  cur[256 + tid] += half0;
  __syncthreads();
  int n0 = tid, n1 = tid + 256;
  int ex0 = cur[n0] - h2[n0];
  int ex1 = cur[n1] - h2[n1];
  eoff[b*512 + n0] = e0 + ex0; ecnt[b*512 + n0] = h2[n0];
  eoff[b*512 + n1] = e0 + ex1; ecnt[b*512 + n1] = h2[n1];
  __syncthreads();
  cur[n0] = e0 + ex0; cur[n1] = e0 + ex1;
  __syncthreads();
  for (int i = e0 + tid; i < e1; i += 256){
    uint2 u = pair[i];
    int pos = atomicAdd(&cur[u.y], 1);
    csr[pos] = (int)u.x;
  }
}

__global__ void k_dinv(const int* __restrict__ ecnt, float* __restrict__ dinv){
  int i = blockIdx.x*256 + threadIdx.x;
  if (i < NN) dinv[i] = 1.0f / sqrtf((float)(ecnt[i] + 1));  // deg = indeg + self-loop >= 1
}

// ---------------- xa = x @ w1 : stage x rows via LDS ----------------
__global__ void k_lin1(const float* __restrict__ x, const float* __restrict__ w1,
                       float* __restrict__ xa){
  __shared__ float w[FIN*HG];       // 864
  __shared__ float xs[16][FIN+2];   // pad to 56
  int tid = threadIdx.x;
  for (int i = tid; i < FIN*HG; i += 256) w[i] = w1[i];
  const float4* gx = (const float4*)(x + (size_t)blockIdx.x*16*FIN);
  if (tid < 216){
    float4 v4 = gx[tid];
    int fi = tid*4;
#pragma unroll
    for (int e = 0; e < 4; e++){
      int idx = fi + e;
      xs[idx/FIN][idx%FIN] = ((const float*)&v4)[e];
    }
  }
  __syncthreads();
  int node = tid >> 4, f = tid & 15;
  const float* xr = xs[node];
  float acc = 0.0f;
#pragma unroll
  for (int k = 0; k < FIN; k++) acc = fmaf(xr[k], w[k*HG + f], acc);
  xa[((size_t)blockIdx.x*16 + node)*HG + f] = acc;
}

// ---------------- gather conv (no atomics): 16 lanes per dst node ----------------
__global__ void k_gather(const float* __restrict__ v, const int* __restrict__ csr,
                         const int* __restrict__ eoff, const int* __restrict__ ecnt,
                         const float* __restrict__ dinv, const float* __restrict__ bias,
                         int dorelu, float* __restrict__ out){
  int gid = blockIdx.x*16 + (threadIdx.x >> 4);
  int f = threadIdx.x & 15;
  float dv = dinv[gid];
  float a0 = v[(size_t)gid*HG + f] * dv, a1 = 0.0f, a2 = 0.0f, a3 = 0.0f;
  int o = eoff[gid], n = ecnt[gid];
  int i = 0;
  for (; i + 8 <= n; i += 8){
    int s0 = csr[o+i],   s1 = csr[o+i+1], s2 = csr[o+i+2], s3 = csr[o+i+3];
    int s4 = csr[o+i+4], s5 = csr[o+i+5], s6 = csr[o+i+6], s7 = csr[o+i+7];
    a0 = fmaf(v[(size_t)s0*HG + f], dinv[s0], a0);
    a1 = fmaf(v[(size_t)s1*HG + f], dinv[s1], a1);
    a2 = fmaf(v[(size_t)s2*HG + f], dinv[s2], a2);
    a3 = fmaf(v[(size_t)s3*HG + f], dinv[s3], a3);
    a0 = fmaf(v[(size_t)s4*HG + f], dinv[s4], a0);
    a1 = fmaf(v[(size_t)s5*HG + f], dinv[s5], a1);
    a2 = fmaf(v[(size_t)s6*HG + f], dinv[s6], a2);
    a3 = fmaf(v[(size_t)s7*HG + f], dinv[s7], a3);
  }
  for (; i + 4 <= n; i += 4){
    int s0 = csr[o+i], s1 = csr[o+i+1], s2 = csr[o+i+2], s3 = csr[o+i+3];
    a0 = fmaf(v[(size_t)s0*HG + f], dinv[s0], a0);
    a1 = fmaf(v[(size_t)s1*HG + f], dinv[s1], a1);
    a2 = fmaf(v[(size_t)s2*HG + f], dinv[s2], a2);
    a3 = fmaf(v[(size_t)s3*HG + f], dinv[s3], a3);
  }
  for (; i < n; i++){
    int s = csr[o+i];
    a0 = fmaf(v[(size_t)s*HG + f], dinv[s], a0);
  }
  float acc = ((a0 + a1) + (a2 + a3)) * dv;
  if (dorelu) acc = fmaxf(acc + bias[f], 0.0f);
  out[(size_t)gid*HG + f] = acc;
}

// ---------------- hb = relu(agg + b1) @ w2 ----------------
__global__ void k_relu_lin(const float* __restrict__ agg, const float* __restrict__ b1,
                           const float* __restrict__ w2, float* __restrict__ hb){
  __shared__ float w[HG*HG];
  __shared__ float bb[HG];
  int tid = threadIdx.x;
  if (tid < HG*HG) w[tid] = w2[tid];
  if (tid < HG) bb[tid] = b1[tid];
  __syncthreads();
  int id = blockIdx.x*256 + tid;
  if (id >= NN*HG) return;
  int node = id >> 4, f = id & 15;
  const float* ar = agg + (size_t)node*HG;
  float acc = 0.0f;
#pragma unroll
  for (int k = 0; k < HG; k++){
    float h = fmaxf(ar[k] + bb[k], 0.0f);
    acc = fmaf(h, w[k*HG + f], acc);
  }
  hb[id] = acc;
}

// ============ BiLSTM: 1 wave per chain, zero barriers, latency-pipelined ===
// Lane layout: lane = half*32 + j; half0 owns {i_j, g_j}, half1 owns {f_j, o_j}.
// Cross-half exchange via __shfl_xor(,32) (proven bitwise-correct).
// h broadcast via same-wave LDS write -> register reload after the write.
// R5 CONFIGURATION RESTORED (best verified: 949 µs). Six structural attempts
// at the ~1600cy/step latency floor all failed or regressed:
//   R6 register-X (VGPR cap spill, 4x), R7 readlane->SGPR (serial readlanes,
//   +35%), R8 SW-pipeline (null - compiler already overlaps), R9
//   producer/consumer ring (+10% - spin+ring read == GATES issue).
// The step floor is the serial chain (hbuf RAW + exchange + trans ops) at
// 1 wave/SIMD; issue-count-independent (lstm0 160 inst/step == lstm1 350).

// shared tail macro (both kernels): from accumulators a0..a3/b0..b3 to cn/hn
#define LTAIL() \
  float uA = (a0 + a1) + (a2 + a3); \
  float uB = (b0 + b1) + (b2 + b3); \
  float aA = sigf(uA); \
  float ub2 = half ? uB : (uB + uB); \
  float sv = sigf(ub2); \
  float aB = half ? sv : (sv + sv - 1.0f); \
  float pq = aA*aB; \
  float part = __shfl_xor(half ? aA : pq, 32); \
  float f_ = half ? aA : part; \
  float p_ = half ? part : pq; \
  float cn = fmaf(f_, c, p_); \
  float th = tanhfast(cn); \
  float ov = __shfl_xor(aB, 32); \
  float o_ = half ? aB : ov; \
  float hn = o_ * th;

// ---------------- layer 0 (R5 version) ----------------
__global__ __launch_bounds__(64, 1) void k_lstm0(
    const float* __restrict__ h2in, const int* __restrict__ starts, const int* __restrict__ counts,
    const float* __restrict__ wih, const float* __restrict__ whh,
    const float* __restrict__ bih, const float* __restrict__ bhh,
    float* __restrict__ out0, int* __restrict__ tconv, int* __restrict__ az)
{
  const int g = blockIdx.x >> 1, dir = blockIdx.x & 1;
  const int lane = threadIdx.x;            // 0..63
  const int j = lane & 31, half = lane >> 5;
  const int rA = (half ? 32 : 0) + j;      // i_j (half0) or f_j (half1)
  const int rB = rA + 64;                  // g_j (half0) or o_j (half1)
  float wxA[HG], wxB[HG], whA[HL], whB[HL];
  { const float4* a4 = (const float4*)(wih + ((size_t)dir*128 + rA)*HG);
    const float4* b4 = (const float4*)(wih + ((size_t)dir*128 + rB)*HG);
#pragma unroll
    for (int k = 0; k < HG/4; k++){ ((float4*)wxA)[k] = a4[k]; ((float4*)wxB)[k] = b4[k]; }
    const float4* ua4 = (const float4*)(whh + ((size_t)dir*128 + rA)*HL);
    const float4* ub4 = (const float4*)(whh + ((size_t)dir*128 + rB)*HL);
#pragma unroll
    for (int k = 0; k < HL/4; k++){ ((float4*)whA)[k] = ua4[k]; ((float4*)whB)[k] = ub4[k]; }
  }
  const float pbA = bih[dir*128 + rA] + bhh[dir*128 + rA];
  const float pbB = bih[dir*128 + rB] + bhh[dir*128 + rB];
  int cnt = counts[g]; if (cnt > TS) cnt = TS;
  const int s0 = starts[g];
  float* outg = out0 + (size_t)g*TS*64 + dir*32;

  __shared__ __align__(16) float hbuf[HL];

  unsigned long long bz = __ballot((pbA == 0.0f) && (pbB == 0.0f));
  bool allzero = (bz == ~0ull);
  if (dir == 1 && lane == 0) az[0] = allzero ? 1 : 0;
  if (!half) hbuf[j] = 0.0f;
  float4 H[8];
  { const float4* h4r = (const float4*)hbuf;
#pragma unroll
    for (int q = 0; q < 8; q++) H[q] = h4r[q]; }

  float c = 0.0f, h = 0.0f;
  int t, dt, tendF;

#define L0_HFMA() \
  _Pragma("unroll") \
  for (int q = 0; q < 8; q++){ float4 hq = H[q]; \
    a0 = fmaf(hq.x, whA[4*q+0], a0); a1 = fmaf(hq.y, whA[4*q+1], a1); \
    a2 = fmaf(hq.z, whA[4*q+2], a2); a3 = fmaf(hq.w, whA[4*q+3], a3); \
    b0 = fmaf(hq.x, whB[4*q+0], b0); b1 = fmaf(hq.y, whB[4*q+1], b1); \
    b2 = fmaf(hq.z, whB[4*q+2], b2); b3 = fmaf(hq.w, whB[4*q+3], b3); }

#define L0_STORE() \
  c = cn; h = hn; \
  if (!half) hbuf[j] = h; \
  { const float4* h4r = (const float4*)hbuf; \
    _Pragma("unroll") for (int q = 0; q < 8; q++) H[q] = h4r[q]; } \
  if (half) outg[(size_t)t*64 + j] = h;

#define L0_F(P) { \
  if (t == tendF) goto l0_fdone; \
  float a0 = pbA, a1 = 0.0f, a2 = 0.0f, a3 = 0.0f; \
  float b0 = pbB, b1 = 0.0f, b2 = 0.0f, b3 = 0.0f; \
  _Pragma("unroll") \
  for (int q = 0; q < 4; q++){ float4 xq = XR##P[q]; \
    a0 = fmaf(xq.x, wxA[4*q+0], a0); a1 = fmaf(xq.y, wxA[4*q+1], a1); \
    a2 = fmaf(xq.z, wxA[4*q+2], a2); a3 = fmaf(xq.w, wxA[4*q+3], a3); \
    b0 = fmaf(xq.x, wxB[4*q+0], b0); b1 = fmaf(xq.y, wxB[4*q+1], b1); \
    b2 = fmaf(xq.z, wxB[4*q+2], b2); b3 = fmaf(xq.w, wxB[4*q+3], b3); } \
  { int tp = t + 4*dt; tp = tp < 0 ? 0 : (tp > cnt-1 ? cnt-1 : tp); \
    const float* pp = h2in + (size_t)(s0 + tp)*HG; \
    XR##P[0] = uload4(pp); XR##P[1] = uload4(pp+4); \
    XR##P[2] = uload4(pp+8); XR##P[3] = uload4(pp+12); } \
  L0_HFMA(); \
  LTAIL(); \
  L0_STORE(); \
  t += dt; }

  // dir1 non-az pre-phase: zero-input descending steps TS-1 .. cnt
  if (dir == 1 && !allzero){
    for (t = TS - 1; t >= cnt; t--){
      float a0 = pbA, a1 = 0.0f, a2 = 0.0f, a3 = 0.0f;
      float b0 = pbB, b1 = 0.0f, b2 = 0.0f, b3 = 0.0f;
      L0_HFMA();
      LTAIL();
      L0_STORE();
    }
  }

  // full phase over real rows, 4-deep rolling register prefetch
  if (cnt > 0){
    if (dir == 0){ t = 0; dt = 1; tendF = cnt; }
    else { t = cnt - 1; dt = -1; tendF = -1; }
    if (!(dir == 1 && t < 0)){
      float4 XR0[4], XR1[4], XR2[4], XR3[4];
      { int r1 = t + dt, r2 = t + 2*dt, r3 = t + 3*dt;
        r1 = r1 < 0 ? 0 : (r1 > cnt-1 ? cnt-1 : r1);
        r2 = r2 < 0 ? 0 : (r2 > cnt-1 ? cnt-1 : r2);
        r3 = r3 < 0 ? 0 : (r3 > cnt-1 ? cnt-1 : r3);
        const float* p0 = h2in + (size_t)(s0 + t)*HG;
        const float* p1 = h2in + (size_t)(s0 + r1)*HG;
        const float* p2 = h2in + (size_t)(s0 + r2)*HG;
        const float* p3 = h2in + (size_t)(s0 + r3)*HG;
        XR0[0]=uload4(p0); XR0[1]=uload4(p0+4); XR0[2]=uload4(p0+8); XR0[3]=uload4(p0+12);
        XR1[0]=uload4(p1); XR1[1]=uload4(p1+4); XR1[2]=uload4(p1+8); XR1[3]=uload4(p1+12);
        XR2[0]=uload4(p2); XR2[1]=uload4(p2+4); XR2[2]=uload4(p2+8); XR2[3]=uload4(p2+12);
        XR3[0]=uload4(p3); XR3[1]=uload4(p3+4); XR3[2]=uload4(p3+8); XR3[3]=uload4(p3+12);
      }
      for (;;){ L0_F(0); L0_F(1); L0_F(2); L0_F(3); }
l0_fdone: ;
    }
  }

  // dir0 zero-input tail with convergence detection
  if (dir == 0){
    bool fwdconv = false;
    for (t = cnt; t < TS; t++){
      float a0 = pbA, a1 = 0.0f, a2 = 0.0f, a3 = 0.0f;
      float b0 = pbB, b1 = 0.0f, b2 = 0.0f, b3 = 0.0f;
      L0_HFMA();
      LTAIL();
      bool eq = (fabsf(cn - c) <= CEPS*(1.0f + fabsf(cn))) && (fabsf(hn - h) <= HEPS);
      L0_STORE();
      unsigned long long m = __ballot(eq);
      if (t >= cnt + 1 && m == ~0ull){
        // state (approx) fixed under constant zero input; rows > t never read
        if (lane == 0) tconv[g] = t - 1;
        fwdconv = true;
        break;
      }
    }
    if (!fwdconv && lane == 0) tconv[g] = TS;
  }
#undef L0_F
#undef L0_STORE
#undef L0_HFMA
}

// ---------------- layer 1 + mean pool (R5 version) ----------------
// x row staged via per-wave LDS ping-pong; the per-lane load feeding the stage
// runs 4 steps ahead (v1..v3 register chain). Phase structure: full / cheap-
// const with convergence closure (dir0), cheap-first then full (dir1).
__global__ __launch_bounds__(64, 1) void k_lstm1(
    const float* __restrict__ gl0, const int* __restrict__ tconv,
    const int* __restrict__ counts, const int* __restrict__ az,
    const float* __restrict__ wih, const float* __restrict__ whh,
    const float* __restrict__ bih, const float* __restrict__ bhh,
    float* __restrict__ pooled)
{
  const int g = blockIdx.x >> 1, dir = blockIdx.x & 1;
  const int lane = threadIdx.x;
  const int j = lane & 31, half = lane >> 5;
  const int rA = (half ? 32 : 0) + j, rB = rA + 64;
  float wxA[64], wxB[64], whA[HL], whB[HL];
  { const float4* A4 = (const float4*)(wih + ((size_t)dir*128 + rA)*64);
    const float4* B4 = (const float4*)(wih + ((size_t)dir*128 + rB)*64);
#pragma unroll
    for (int k = 0; k < 16; k++){ ((float4*)wxA)[k] = A4[k]; ((float4*)wxB)[k] = B4[k]; }
    const float4* a4 = (const float4*)(whh + ((size_t)dir*128 + rA)*HL);
    const float4* b4 = (const float4*)(whh + ((size_t)dir*128 + rB)*HL);
#pragma unroll
    for (int k = 0; k < 8; k++){ ((float4*)whA)[k] = a4[k]; ((float4*)whB)[k] = b4[k]; }
  }
  const float pbA = bih[dir*128 + rA] + bhh[dir*128 + rA];
  const float pbB = bih[dir*128 + rB] + bhh[dir*128 + rB];
  const float* gin = gl0 + (size_t)g*TS*64;
  const int tcv = tconv[g];
  int cnt = counts[g]; if (cnt > TS) cnt = TS;
  const bool mz = (az[0] != 0) && (half != 0);   // mask hi columns of rows >= cnt

  __shared__ __align__(16) float hbuf[HL];
  __shared__ __align__(16) float xrow[2][64];

  if (!half) hbuf[j] = 0.0f;

  float c = 0.0f, h = 0.0f, hsum = 0.0f;

#define L1_GATES(XPTR) \
  float a0 = pbA, a1 = 0.0f, a2 = 0.0f, a3 = 0.0f; \
  float b0 = pbB, b1 = 0.0f, b2 = 0.0f, b3 = 0.0f; \
  { const float4* xp_ = (const float4*)(XPTR); \
    _Pragma("unroll") \
    for (int q = 0; q < 16; q++){ float4 xq = xp_[q]; \
      a0 = fmaf(xq.x, wxA[4*q+0], a0); a1 = fmaf(xq.y, wxA[4*q+1], a1); \
      a2 = fmaf(xq.z, wxA[4*q+2], a2); a3 = fmaf(xq.w, wxA[4*q+3], a3); \
      b0 = fmaf(xq.x, wxB[4*q+0], b0); b1 = fmaf(xq.y, wxB[4*q+1], b1); \
      b2 = fmaf(xq.z, wxB[4*q+2], b2); b3 = fmaf(xq.w, wxB[4*q+3], b3); } }

#define L1_HFMA() \
  { const float4* h4_ = (const float4*)hbuf; \
    _Pragma("unroll") \
    for (int q = 0; q < HL/4; q++){ float4 hq = h4_[q]; \
      a0 = fmaf(hq.x, whA[4*q+0], a0); a1 = fmaf(hq.y, whA[4*q+1], a1); \
      a2 = fmaf(hq.z, whA[4*q+2], a2); a3 = fmaf(hq.w, whA[4*q+3], a3); \
      b0 = fmaf(hq.x, whB[4*q+0], b0); b1 = fmaf(hq.y, whB[4*q+1], b1); \
      b2 = fmaf(hq.z, whB[4*q+2], b2); b3 = fmaf(hq.w, whB[4*q+3], b3); } }

#define L1_STORE() \
  c = cn; h = hn; hsum += h; \
  if (!half) hbuf[j] = h;

  if (dir == 0){
    // ---- full phase: t = 0 .. min(tcv, TS-1) ----
    const int tend = (tcv < TS-1) ? tcv : TS-1;
    { float x0 = gin[lane];
      if (mz && 0 >= cnt) x0 = 0.0f;
      xrow[0][lane] = x0; }
    float v1 = gin[64 + lane], v2 = gin[128 + lane], v3 = gin[192 + lane];
    int ph = 0;
    for (int t = 0; t <= tend; t++){
      L1_GATES(xrow[ph]);
      { int tn = t + 1; float xw = (mz && tn >= cnt) ? 0.0f : v1;
        xrow[ph^1][lane] = xw; }                 // row t+1 (load 4 steps old)
      v1 = v2; v2 = v3;
      { int tp = t + 4; if (tp > TS-1) tp = TS-1;
        v3 = gin[(size_t)tp*64 + lane]; }        // issue row t+4, stays in flight
      L1_HFMA();
      LTAIL();
      L1_STORE();
      ph ^= 1;
    }
    // ---- cheap phase: rows >= tcv+1 bitwise equal; xrow[ph] holds row tcv+1 ----
    if (tcv < TS-1){
      float xc0 = pbA, xc1 = 0.0f, xc2 = 0.0f, xc3 = 0.0f;
      float yc0 = pbB, yc1 = 0.0f, yc2 = 0.0f, yc3 = 0.0f;
      { const float4* xp = (const float4*)xrow[ph];
#pragma unroll
        for (int q = 0; q < 16; q++){ float4 xq = xp[q];
          xc0 = fmaf(xq.x, wxA[4*q+0], xc0); xc1 = fmaf(xq.y, wxA[4*q+1], xc1);
          xc2 = fmaf(xq.z, wxA[4*q+2], xc2); xc3 = fmaf(xq.w, wxA[4*q+3], xc3);
          yc0 = fmaf(xq.x, wxB[4*q+0], yc0); yc1 = fmaf(xq.y, wxB[4*q+1], yc1);
          yc2 = fmaf(xq.z, wxB[4*q+2], yc2); yc3 = fmaf(xq.w, wxB[4*q+3], yc3); } }
      for (int t = tcv+1; t < TS; t++){
        float a0 = xc0, a1 = xc1, a2 = xc2, a3 = xc3;
        float b0 = yc0, b1 = yc1, b2 = yc2, b3 = yc3;
        L1_HFMA();
        LTAIL();
        bool eq = (fabsf(cn - c) <= CEPS*(1.0f + fabsf(cn))) && (fabsf(hn - h) <= HEPS);
        L1_STORE();
        unsigned long long m = __ballot(eq);
        if (m == ~0ull){ hsum += h * (float)(TS-1 - t); break; }  // fixed point
      }
    }
  } else {
    // ---- dir 1: cheap phase first (rows TS-1..tcv+1 bitwise equal) ----
    int tfull;
    if (tcv + 1 <= TS - 1){
      { float x0 = gin[(size_t)(tcv+1)*64 + lane];
        if (mz && tcv+1 >= cnt) x0 = 0.0f;
        xrow[0][lane] = x0; }                    // constant row content
      float xc0 = pbA, xc1 = 0.0f, xc2 = 0.0f, xc3 = 0.0f;
      float yc0 = pbB, yc1 = 0.0f, yc2 = 0.0f, yc3 = 0.0f;
      { const float4* xp = (const float4*)xrow[0];
#pragma unroll
        for (int q = 0; q < 16; q++){ float4 xq = xp[q];
          xc0 = fmaf(xq.x, wxA[4*q+0], xc0); xc1 = fmaf(xq.y, wxA[4*q+1], xc1);
          xc2 = fmaf(xq.z, wxA[4*q+2], xc2); xc3 = fmaf(xq.w, wxA[4*q+3], xc3);
          yc0 = fmaf(xq.x, wxB[4*q+0], yc0); yc1 = fmaf(xq.y, wxB[4*q+1], yc1);
          yc2 = fmaf(xq.z, wxB[4*q+2], yc2); yc3 = fmaf(xq.w, wxB[4*q+3], yc3); } }
      int t = TS - 1; bool jumped = false;
      for (; t >= tcv + 1; t--){
        float a0 = xc0, a1 = xc1, a2 = xc2, a3 = xc3;
        float b0 = yc0, b1 = yc1, b2 = yc2, b3 = yc3;
        L1_HFMA();
        LTAIL();
        bool eq = (fabsf(cn - c) <= CEPS*(1.0f + fabsf(cn))) && (fabsf(hn - h) <= HEPS);
        L1_STORE();
        unsigned long long m = __ballot(eq);
        if (m == ~0ull){ hsum += h * (float)(t - tcv); jumped = true; break; }
      }
      tfull = jumped ? (tcv - 1) : tcv;
    } else tfull = TS - 1;
    // ---- full descending phase: t = tfull .. 0 ----
    if (tfull >= 0){
      { float x0 = gin[(size_t)tfull*64 + lane];
        if (mz && tfull >= cnt) x0 = 0.0f;
        xrow[0][lane] = x0; }
      int r1 = tfull-1 < 0 ? 0 : tfull-1;
      int r2 = tfull-2 < 0 ? 0 : tfull-2;
      int r3 = tfull-3 < 0 ? 0 : tfull-3;
      float v1 = gin[(size_t)r1*64 + lane];
      float v2 = gin[(size_t)r2*64 + lane];
      float v3 = gin[(size_t)r3*64 + lane];
      int ph = 0;
      for (int t = tfull; t >= 0; t--){
        L1_GATES(xrow[ph]);
        { int tn = t - 1; float xw = (mz && tn >= cnt) ? 0.0f : v1;
          xrow[ph^1][lane] = xw; }               // row t-1
        v1 = v2; v2 = v3;
        { int tp = t - 4; if (tp < 0) tp = 0;
          v3 = gin[(size_t)tp*64 + lane]; }
        L1_HFMA();
        LTAIL();
        L1_STORE();
        ph ^= 1;
      }
    }
  }
  if (!half) pooled[(size_t)g*64 + dir*32 + j] = hsum * (1.0f/(float)TS);
#undef L1_GATES
#undef L1_HFMA
#undef L1_STORE
}

// ---------------- FC: out = pooled @ fc_w + fc_b ----------------
__global__ void k_fc(const float* __restrict__ pooled, const float* __restrict__ fcw,
                     const float* __restrict__ fcb, float* __restrict__ out){
  __shared__ float p[64];
  int g = blockIdx.x, cix = threadIdx.x;
  if (cix < 64) p[cix] = pooled[(size_t)g*64 + cix];
  __syncthreads();
  float acc = fcb[cix];
#pragma unroll
  for (int k = 0; k < 64; k++) acc = fmaf(p[k], fcw[k*NC + cix], acc);
  out[(size_t)g*NC + cix] = acc;
}

extern "C" void kernel_launch(void* const* d_in, const int* in_sizes, int n_in,
                              void* d_out, int out_size, void* d_ws, size_t ws_size,
                              hipStream_t stream) {
  const float* x        = (const float*)d_in[0];
  const int*   ei       = (const int*)  d_in[1];
  const int*   batch    = (const int*)  d_in[2];
  const float* gcn_w1   = (const float*)d_in[3];
  const float* gcn_b1   = (const float*)d_in[4];
  const float* gcn_w2   = (const float*)d_in[5];
  const float* gcn_b2   = (const float*)d_in[6];
  const float* l0_wih   = (const float*)d_in[7];
  const float* l0_whh   = (const float*)d_in[8];
  const float* l0_bih   = (const float*)d_in[9];
  const float* l0_bhh   = (const float*)d_in[10];
  const float* l1_wih   = (const float*)d_in[11];
  const float* l1_whh   = (const float*)d_in[12];
  const float* l1_bih   = (const float*)d_in[13];
  const float* l1_bhh   = (const float*)d_in[14];
  const float* fc_w     = (const float*)d_in[15];
  const float* fc_b     = (const float*)d_in[16];
  float* out = (float*)d_out;

  // workspace layout (4B units)
  float* ws   = (float*)d_ws;
  float* B0   = ws;                        // NN*16
  float* B1   = B0 + (size_t)NN*HG;        // NN*16
  float* B2   = B1 + (size_t)NN*HG;        // NN*16
  float* dinv = B2 + (size_t)NN*HG;        // NN
  int*   ecnt   = (int*)(dinv + NN);       // NN
  int*   eoff   = ecnt + NN;               // NN
  int*   hist   = eoff + NN;               // NB*WH = 131072
  int*   offs   = hist + NB*WH;            // 131072
  int*   counts = offs + NB*WH;            // 512
  int*   starts = counts + NG;             // 512
  int*   tconv  = starts + NG;             // 512
  int*   bstart = tconv + NG;              // NB+1
  int*   az     = bstart + NB + 4;         // 1 (inside 64-int pad)
  float* pooled = (float*)(bstart + NB + 64);      // 512*64 (64-int pad)
  int*   csr    = (int*)(pooled + (size_t)NG*64);  // NE
  float* out0   = (float*)(csr + (size_t)NE);      // 512*1024*64
  uint2* pair   = (uint2*)out0;                    // NE*2 ints, aliases out0 (dead before lstm0)
  size_t needed = ((size_t)((float*)out0 - ws) + (size_t)NG*TS*64) * sizeof(float);
  if (ws_size < needed) return;  // fail loudly (poisoned d_out) rather than corrupt

  k_initc <<<1, NG, 0, stream>>>(counts);
  k_cnt   <<<NN/256, 256, 0, stream>>>(batch, counts);
  k_hist  <<<WH, 256, 0, stream>>>(ei, hist);
  k_scanH <<<1, 1024, 0, stream>>>(hist, offs, bstart);
  k_scan  <<<1, NG, 0, stream>>>(counts, starts);
  k_binB  <<<WH, 256, 0, stream>>>(ei, offs, pair);
  k_binC  <<<NB, 256, 0, stream>>>(pair, bstart, eoff, ecnt, csr);
  k_dinv  <<<NN/256, 256, 0, stream>>>(ecnt, dinv);
  k_lin1  <<<NN/16, 256, 0, stream>>>(x, gcn_w1, B0);
  k_gather<<<(NN*HG)/256, 256, 0, stream>>>(B0, csr, eoff, ecnt, dinv, gcn_b2, 0, B1);
  k_relu_lin<<<(NN*HG)/256, 256, 0, stream>>>(B1, gcn_b1, gcn_w2, B2);
  k_gather<<<(NN*HG)/256, 256, 0, stream>>>(B2, csr, eoff, ecnt, dinv, gcn_b2, 1, B1);
  k_lstm0 <<<NG*2, 64, 0, stream>>>(B1, starts, counts, l0_wih, l0_whh, l0_bih, l0_bhh, out0, tconv, az);
  k_lstm1 <<<NG*2, 64, 0, stream>>>(out0, tconv, counts, az, l1_wih, l1_whh, l1_bih, l1_bhh, pooled);
  k_fc    <<<NG, NC, 0, stream>>>(pooled, fc_w, fc_b, out);
}

// Round 11
// 837.010 us; speedup vs baseline: 1.1889x; 1.1484x over previous
//
#include <hip/hip_runtime.h>
#include <cstdint>
#include <cstddef>

#define NG 512        // NUM_GRAPHS
#define NN 131072     // N_NODES
#define NE 4194304    // N_EDGES
#define FIN 54        // F_IN
#define HG 16         // H_GCN
#define HL 32         // H_LSTM
#define NC 192        // N_CLASSES
#define TS 1024       // MAX_SEQ_LEN

#define NB 256        // dst buckets (dst>>9), 512 nodes each
#define WH 512        // histogram/scatter workgroups, 8192 edges each
#define EPW (NE/WH)   // 8192

__device__ __forceinline__ float rcpf(float x){ return __builtin_amdgcn_rcpf(x); }
__device__ __forceinline__ float sigf(float x){ return rcpf(1.0f + __expf(-x)); }
__device__ __forceinline__ float tanhfast(float x){ return 1.0f - 2.0f*rcpf(__expf(2.0f*x) + 1.0f); }

// Wave-uniform row load kept in the VECTOR (vmcnt) domain (s_load shares
// lgkmcnt with DS -> serializing waits in the LDS-heavy step).
__device__ __forceinline__ float4 uload4(const float* p){
  unsigned long long a = (unsigned long long)p;
  asm volatile("" : "+v"(a));
  return *(const float4*)a;
}

#define CEPS 1e-6f
#define HEPS 1e-6f

// ---------------- segment bounds from SORTED batch ----------------
// batch is jnp.sort'ed -> st[g] = first index with batch[i] >= g (exclusive
// prefix of counts, identical to the old initc+cnt+scan pipeline, no atomics).
// st has NG+1 entries; st[NG] = NN. Empty graphs handled by the bp+1..b fill.
__global__ void k_bounds(const int* __restrict__ batch, int* __restrict__ st){
  int i = blockIdx.x*256 + threadIdx.x;
  if (i >= NN) return;
  int b = batch[i];
  int bp = (i == 0) ? -1 : batch[i-1];
  for (int g = bp+1; g <= b; g++) st[g] = i;
  if (i == NN-1){
    for (int g = b+1; g <= NG; g++) st[g] = NN;
  }
}

// ---------------- bucket histogram: hist[b*WH + w] ----------------
__global__ void k_hist(const int* __restrict__ ei, int* __restrict__ hist){
  int w = blockIdx.x, tid = threadIdx.x;
  __shared__ int h[NB];
  h[tid] = 0;
  __syncthreads();
  int e0 = w*EPW;
  for (int i = tid; i < EPW; i += 256) atomicAdd(&h[ei[NE + e0 + i] >> 9], 1);
  __syncthreads();
  hist[tid*WH + w] = h[tid];
}

// ---------------- scan 131072-entry histogram (1 block, 1024 thr) ----------------
__global__ void k_scanH(const int* __restrict__ hist, int* __restrict__ offs,
                        int* __restrict__ bstart){
  __shared__ int tot[1024];
  int t = threadIdx.x;
  int base = t*128;
  int s = 0;
  for (int i = 0; i < 128; i++) s += hist[base + i];
  tot[t] = s; __syncthreads();
  for (int o = 1; o < 1024; o <<= 1){
    int v = (t >= o) ? tot[t-o] : 0;
    __syncthreads();
    tot[t] += v;
    __syncthreads();
  }
  int run = tot[t] - s;
  for (int i = 0; i < 128; i++){
    int idx = base + i;
    int h = hist[idx];
    offs[idx] = run;
    if ((idx & (WH-1)) == 0) bstart[idx / WH] = run;
    run += h;
  }
  if (t == 0) bstart[NB] = NE;
}

// ---------------- bin pass B: scatter (src, dst&511) into bucket-sorted pairs ----------------
__global__ void k_binB(const int* __restrict__ ei, const int* __restrict__ offs,
                       uint2* __restrict__ pair){
  int w = blockIdx.x, tid = threadIdx.x;
  __shared__ int cur[NB];
  cur[tid] = offs[tid*WH + w];
  __syncthreads();
  int e0 = w*EPW;
  for (int i = tid; i < EPW; i += 256){
    int e = e0 + i;
    int s = ei[e], d = ei[NE + e];
    int b = d >> 9;
    int pos = atomicAdd(&cur[b], 1);
    pair[pos] = make_uint2((unsigned)s, (unsigned)(d & 511));
  }
}

// ---------------- bin pass C: per-bucket CSR finalize (one wg per bucket) ----------------
// Also emits dinv (deg = indeg + self-loop >= 1) -- folds the old k_dinv sweep
// (same 1.0f/sqrtf expression -> bitwise identical).
__global__ void k_binC(const uint2* __restrict__ pair, const int* __restrict__ bstart,
                       int* __restrict__ eoff, int* __restrict__ ecnt, int* __restrict__ csr,
                       float* __restrict__ dinv){
  int b = blockIdx.x, tid = threadIdx.x;
  __shared__ int h2[512];
  __shared__ int cur[512];
  h2[tid] = 0; h2[tid + 256] = 0;
  __syncthreads();
  int e0 = bstart[b], e1 = bstart[b+1];
  for (int i = e0 + tid; i < e1; i += 256) atomicAdd(&h2[pair[i].y], 1);
  __syncthreads();
  cur[tid] = h2[tid]; cur[tid + 256] = h2[tid + 256];
  __syncthreads();
  for (int o = 1; o < 256; o <<= 1){
    int v0 = (tid >= o) ? cur[tid - o] : 0;
    int v1 = (tid >= o) ? cur[256 + tid - o] : 0;
    __syncthreads();
    cur[tid] += v0; cur[256 + tid] += v1;
    __syncthreads();
  }
  int half0 = cur[255];
  __syncthreads();
  cur[256 + tid] += half0;
  __syncthreads();
  int n0 = tid, n1 = tid + 256;
  int ex0 = cur[n0] - h2[n0];
  int ex1 = cur[n1] - h2[n1];
  eoff[b*512 + n0] = e0 + ex0; ecnt[b*512 + n0] = h2[n0];
  eoff[b*512 + n1] = e0 + ex1; ecnt[b*512 + n1] = h2[n1];
  dinv[b*512 + n0] = 1.0f / sqrtf((float)(h2[n0] + 1));
  dinv[b*512 + n1] = 1.0f / sqrtf((float)(h2[n1] + 1));
  __syncthreads();
  cur[n0] = e0 + ex0; cur[n1] = e0 + ex1;
  __syncthreads();
  for (int i = e0 + tid; i < e1; i += 256){
    uint2 u = pair[i];
    int pos = atomicAdd(&cur[u.y], 1);
    csr[pos] = (int)u.x;
  }
}

// ---------------- xa = x @ w1 : stage x rows via LDS ----------------
__global__ void k_lin1(const float* __restrict__ x, const float* __restrict__ w1,
                       float* __restrict__ xa){
  __shared__ float w[FIN*HG];       // 864
  __shared__ float xs[16][FIN+2];   // pad to 56
  int tid = threadIdx.x;
  for (int i = tid; i < FIN*HG; i += 256) w[i] = w1[i];
  const float4* gx = (const float4*)(x + (size_t)blockIdx.x*16*FIN);
  if (tid < 216){
    float4 v4 = gx[tid];
    int fi = tid*4;
#pragma unroll
    for (int e = 0; e < 4; e++){
      int idx = fi + e;
      xs[idx/FIN][idx%FIN] = ((const float*)&v4)[e];
    }
  }
  __syncthreads();
  int node = tid >> 4, f = tid & 15;
  const float* xr = xs[node];
  float acc = 0.0f;
#pragma unroll
  for (int k = 0; k < FIN; k++) acc = fmaf(xr[k], w[k*HG + f], acc);
  xa[((size_t)blockIdx.x*16 + node)*HG + f] = acc;
}

// ---------------- gather conv (no atomics): 16 lanes per dst node ----------------
__global__ void k_gather(const float* __restrict__ v, const int* __restrict__ csr,
                         const int* __restrict__ eoff, const int* __restrict__ ecnt,
                         const float* __restrict__ dinv, const float* __restrict__ bias,
                         int dorelu, float* __restrict__ out){
  int gid = blockIdx.x*16 + (threadIdx.x >> 4);
  int f = threadIdx.x & 15;
  float dv = dinv[gid];
  float a0 = v[(size_t)gid*HG + f] * dv, a1 = 0.0f, a2 = 0.0f, a3 = 0.0f;
  int o = eoff[gid], n = ecnt[gid];
  int i = 0;
  for (; i + 8 <= n; i += 8){
    int s0 = csr[o+i],   s1 = csr[o+i+1], s2 = csr[o+i+2], s3 = csr[o+i+3];
    int s4 = csr[o+i+4], s5 = csr[o+i+5], s6 = csr[o+i+6], s7 = csr[o+i+7];
    a0 = fmaf(v[(size_t)s0*HG + f], dinv[s0], a0);
    a1 = fmaf(v[(size_t)s1*HG + f], dinv[s1], a1);
    a2 = fmaf(v[(size_t)s2*HG + f], dinv[s2], a2);
    a3 = fmaf(v[(size_t)s3*HG + f], dinv[s3], a3);
    a0 = fmaf(v[(size_t)s4*HG + f], dinv[s4], a0);
    a1 = fmaf(v[(size_t)s5*HG + f], dinv[s5], a1);
    a2 = fmaf(v[(size_t)s6*HG + f], dinv[s6], a2);
    a3 = fmaf(v[(size_t)s7*HG + f], dinv[s7], a3);
  }
  for (; i + 4 <= n; i += 4){
    int s0 = csr[o+i], s1 = csr[o+i+1], s2 = csr[o+i+2], s3 = csr[o+i+3];
    a0 = fmaf(v[(size_t)s0*HG + f], dinv[s0], a0);
    a1 = fmaf(v[(size_t)s1*HG + f], dinv[s1], a1);
    a2 = fmaf(v[(size_t)s2*HG + f], dinv[s2], a2);
    a3 = fmaf(v[(size_t)s3*HG + f], dinv[s3], a3);
  }
  for (; i < n; i++){
    int s = csr[o+i];
    a0 = fmaf(v[(size_t)s*HG + f], dinv[s], a0);
  }
  float acc = ((a0 + a1) + (a2 + a3)) * dv;
  if (dorelu) acc = fmaxf(acc + bias[f], 0.0f);
  out[(size_t)gid*HG + f] = acc;
}

// ---------------- hb = relu(agg + b1) @ w2 ----------------
__global__ void k_relu_lin(const float* __restrict__ agg, const float* __restrict__ b1,
                           const float* __restrict__ w2, float* __restrict__ hb){
  __shared__ float w[HG*HG];
  __shared__ float bb[HG];
  int tid = threadIdx.x;
  if (tid < HG*HG) w[tid] = w2[tid];
  if (tid < HG) bb[tid] = b1[tid];
  __syncthreads();
  int id = blockIdx.x*256 + tid;
  if (id >= NN*HG) return;
  int node = id >> 4, f = id & 15;
  const float* ar = agg + (size_t)node*HG;
  float acc = 0.0f;
#pragma unroll
  for (int k = 0; k < HG; k++){
    float h = fmaxf(ar[k] + bb[k], 0.0f);
    acc = fmaf(h, w[k*HG + f], acc);
  }
  hb[id] = acc;
}

// ============ BiLSTM: 1 wave per chain, zero barriers, latency-pipelined ===
// Lane layout: lane = half*32 + j; half0 owns {i_j, g_j}, half1 owns {f_j, o_j}.
// Cross-half exchange via __shfl_xor(,32) (proven bitwise-correct).
// h broadcast via same-wave LDS write -> register reload after the write.
// R5 configuration (best verified). The ~1600cy/step serial-chain floor stood
// against 6 structural attacks (R3/4 permlane, R6 reg-X spill, R7 readlane,
// R8 SW-pipeline null, R9 producer/consumer). cnt/starts now from st[] bounds.

// shared tail macro (both kernels): from accumulators a0..a3/b0..b3 to cn/hn
#define LTAIL() \
  float uA = (a0 + a1) + (a2 + a3); \
  float uB = (b0 + b1) + (b2 + b3); \
  float aA = sigf(uA); \
  float ub2 = half ? uB : (uB + uB); \
  float sv = sigf(ub2); \
  float aB = half ? sv : (sv + sv - 1.0f); \
  float pq = aA*aB; \
  float part = __shfl_xor(half ? aA : pq, 32); \
  float f_ = half ? aA : part; \
  float p_ = half ? part : pq; \
  float cn = fmaf(f_, c, p_); \
  float th = tanhfast(cn); \
  float ov = __shfl_xor(aB, 32); \
  float o_ = half ? aB : ov; \
  float hn = o_ * th;

// ---------------- layer 0 ----------------
__global__ __launch_bounds__(64, 1) void k_lstm0(
    const float* __restrict__ h2in, const int* __restrict__ st,
    const float* __restrict__ wih, const float* __restrict__ whh,
    const float* __restrict__ bih, const float* __restrict__ bhh,
    float* __restrict__ out0, int* __restrict__ tconv, int* __restrict__ az)
{
  const int g = blockIdx.x >> 1, dir = blockIdx.x & 1;
  const int lane = threadIdx.x;            // 0..63
  const int j = lane & 31, half = lane >> 5;
  const int rA = (half ? 32 : 0) + j;      // i_j (half0) or f_j (half1)
  const int rB = rA + 64;                  // g_j (half0) or o_j (half1)
  float wxA[HG], wxB[HG], whA[HL], whB[HL];
  { const float4* a4 = (const float4*)(wih + ((size_t)dir*128 + rA)*HG);
    const float4* b4 = (const float4*)(wih + ((size_t)dir*128 + rB)*HG);
#pragma unroll
    for (int k = 0; k < HG/4; k++){ ((float4*)wxA)[k] = a4[k]; ((float4*)wxB)[k] = b4[k]; }
    const float4* ua4 = (const float4*)(whh + ((size_t)dir*128 + rA)*HL);
    const float4* ub4 = (const float4*)(whh + ((size_t)dir*128 + rB)*HL);
#pragma unroll
    for (int k = 0; k < HL/4; k++){ ((float4*)whA)[k] = ua4[k]; ((float4*)whB)[k] = ub4[k]; }
  }
  const float pbA = bih[dir*128 + rA] + bhh[dir*128 + rA];
  const float pbB = bih[dir*128 + rB] + bhh[dir*128 + rB];
  const int s0 = st[g];
  int cnt = st[g+1] - s0; if (cnt > TS) cnt = TS;
  float* outg = out0 + (size_t)g*TS*64 + dir*32;

  __shared__ __align__(16) float hbuf[HL];

  unsigned long long bz = __ballot((pbA == 0.0f) && (pbB == 0.0f));
  bool allzero = (bz == ~0ull);
  if (dir == 1 && lane == 0) az[0] = allzero ? 1 : 0;
  if (!half) hbuf[j] = 0.0f;
  float4 H[8];
  { const float4* h4r = (const float4*)hbuf;
#pragma unroll
    for (int q = 0; q < 8; q++) H[q] = h4r[q]; }

  float c = 0.0f, h = 0.0f;
  int t, dt, tendF;

#define L0_HFMA() \
  _Pragma("unroll") \
  for (int q = 0; q < 8; q++){ float4 hq = H[q]; \
    a0 = fmaf(hq.x, whA[4*q+0], a0); a1 = fmaf(hq.y, whA[4*q+1], a1); \
    a2 = fmaf(hq.z, whA[4*q+2], a2); a3 = fmaf(hq.w, whA[4*q+3], a3); \
    b0 = fmaf(hq.x, whB[4*q+0], b0); b1 = fmaf(hq.y, whB[4*q+1], b1); \
    b2 = fmaf(hq.z, whB[4*q+2], b2); b3 = fmaf(hq.w, whB[4*q+3], b3); }

#define L0_STORE() \
  c = cn; h = hn; \
  if (!half) hbuf[j] = h; \
  { const float4* h4r = (const float4*)hbuf; \
    _Pragma("unroll") for (int q = 0; q < 8; q++) H[q] = h4r[q]; } \
  if (half) outg[(size_t)t*64 + j] = h;

#define L0_F(P) { \
  if (t == tendF) goto l0_fdone; \
  float a0 = pbA, a1 = 0.0f, a2 = 0.0f, a3 = 0.0f; \
  float b0 = pbB, b1 = 0.0f, b2 = 0.0f, b3 = 0.0f; \
  _Pragma("unroll") \
  for (int q = 0; q < 4; q++){ float4 xq = XR##P[q]; \
    a0 = fmaf(xq.x, wxA[4*q+0], a0); a1 = fmaf(xq.y, wxA[4*q+1], a1); \
    a2 = fmaf(xq.z, wxA[4*q+2], a2); a3 = fmaf(xq.w, wxA[4*q+3], a3); \
    b0 = fmaf(xq.x, wxB[4*q+0], b0); b1 = fmaf(xq.y, wxB[4*q+1], b1); \
    b2 = fmaf(xq.z, wxB[4*q+2], b2); b3 = fmaf(xq.w, wxB[4*q+3], b3); } \
  { int tp = t + 4*dt; tp = tp < 0 ? 0 : (tp > cnt-1 ? cnt-1 : tp); \
    const float* pp = h2in + (size_t)(s0 + tp)*HG; \
    XR##P[0] = uload4(pp); XR##P[1] = uload4(pp+4); \
    XR##P[2] = uload4(pp+8); XR##P[3] = uload4(pp+12); } \
  L0_HFMA(); \
  LTAIL(); \
  L0_STORE(); \
  t += dt; }

  // dir1 non-az pre-phase: zero-input descending steps TS-1 .. cnt
  if (dir == 1 && !allzero){
    for (t = TS - 1; t >= cnt; t--){
      float a0 = pbA, a1 = 0.0f, a2 = 0.0f, a3 = 0.0f;
      float b0 = pbB, b1 = 0.0f, b2 = 0.0f, b3 = 0.0f;
      L0_HFMA();
      LTAIL();
      L0_STORE();
    }
  }

  // full phase over real rows, 4-deep rolling register prefetch
  if (cnt > 0){
    if (dir == 0){ t = 0; dt = 1; tendF = cnt; }
    else { t = cnt - 1; dt = -1; tendF = -1; }
    if (!(dir == 1 && t < 0)){
      float4 XR0[4], XR1[4], XR2[4], XR3[4];
      { int r1 = t + dt, r2 = t + 2*dt, r3 = t + 3*dt;
        r1 = r1 < 0 ? 0 : (r1 > cnt-1 ? cnt-1 : r1);
        r2 = r2 < 0 ? 0 : (r2 > cnt-1 ? cnt-1 : r2);
        r3 = r3 < 0 ? 0 : (r3 > cnt-1 ? cnt-1 : r3);
        const float* p0 = h2in + (size_t)(s0 + t)*HG;
        const float* p1 = h2in + (size_t)(s0 + r1)*HG;
        const float* p2 = h2in + (size_t)(s0 + r2)*HG;
        const float* p3 = h2in + (size_t)(s0 + r3)*HG;
        XR0[0]=uload4(p0); XR0[1]=uload4(p0+4); XR0[2]=uload4(p0+8); XR0[3]=uload4(p0+12);
        XR1[0]=uload4(p1); XR1[1]=uload4(p1+4); XR1[2]=uload4(p1+8); XR1[3]=uload4(p1+12);
        XR2[0]=uload4(p2); XR2[1]=uload4(p2+4); XR2[2]=uload4(p2+8); XR2[3]=uload4(p2+12);
        XR3[0]=uload4(p3); XR3[1]=uload4(p3+4); XR3[2]=uload4(p3+8); XR3[3]=uload4(p3+12);
      }
      for (;;){ L0_F(0); L0_F(1); L0_F(2); L0_F(3); }
l0_fdone: ;
    }
  }

  // dir0 zero-input tail with convergence detection
  if (dir == 0){
    bool fwdconv = false;
    for (t = cnt; t < TS; t++){
      float a0 = pbA, a1 = 0.0f, a2 = 0.0f, a3 = 0.0f;
      float b0 = pbB, b1 = 0.0f, b2 = 0.0f, b3 = 0.0f;
      L0_HFMA();
      LTAIL();
      bool eq = (fabsf(cn - c) <= CEPS*(1.0f + fabsf(cn))) && (fabsf(hn - h) <= HEPS);
      L0_STORE();
      unsigned long long m = __ballot(eq);
      if (t >= cnt + 1 && m == ~0ull){
        // state (approx) fixed under constant zero input; rows > t never read
        if (lane == 0) tconv[g] = t - 1;
        fwdconv = true;
        break;
      }
    }
    if (!fwdconv && lane == 0) tconv[g] = TS;
  }
#undef L0_F
#undef L0_STORE
#undef L0_HFMA
}

// ---------------- layer 1 + mean pool ----------------
// x row staged via per-wave LDS ping-pong; the per-lane load feeding the stage
// runs 4 steps ahead (v1..v3 register chain). Phase structure: full / cheap-
// const with convergence closure (dir0), cheap-first then full (dir1).
__global__ __launch_bounds__(64, 1) void k_lstm1(
    const float* __restrict__ gl0, const int* __restrict__ tconv,
    const int* __restrict__ st, const int* __restrict__ az,
    const float* __restrict__ wih, const float* __restrict__ whh,
    const float* __restrict__ bih, const float* __restrict__ bhh,
    float* __restrict__ pooled)
{
  const int g = blockIdx.x >> 1, dir = blockIdx.x & 1;
  const int lane = threadIdx.x;
  const int j = lane & 31, half = lane >> 5;
  const int rA = (half ? 32 : 0) + j, rB = rA + 64;
  float wxA[64], wxB[64], whA[HL], whB[HL];
  { const float4* A4 = (const float4*)(wih + ((size_t)dir*128 + rA)*64);
    const float4* B4 = (const float4*)(wih + ((size_t)dir*128 + rB)*64);
#pragma unroll
    for (int k = 0; k < 16; k++){ ((float4*)wxA)[k] = A4[k]; ((float4*)wxB)[k] = B4[k]; }
    const float4* a4 = (const float4*)(whh + ((size_t)dir*128 + rA)*HL);
    const float4* b4 = (const float4*)(whh + ((size_t)dir*128 + rB)*HL);
#pragma unroll
    for (int k = 0; k < 8; k++){ ((float4*)whA)[k] = a4[k]; ((float4*)whB)[k] = b4[k]; }
  }
  const float pbA = bih[dir*128 + rA] + bhh[dir*128 + rA];
  const float pbB = bih[dir*128 + rB] + bhh[dir*128 + rB];
  const float* gin = gl0 + (size_t)g*TS*64;
  const int tcv = tconv[g];
  int cnt = st[g+1] - st[g]; if (cnt > TS) cnt = TS;
  const bool mz = (az[0] != 0) && (half != 0);   // mask hi columns of rows >= cnt

  __shared__ __align__(16) float hbuf[HL];
  __shared__ __align__(16) float xrow[2][64];

  if (!half) hbuf[j] = 0.0f;

  float c = 0.0f, h = 0.0f, hsum = 0.0f;

#define L1_GATES(XPTR) \
  float a0 = pbA, a1 = 0.0f, a2 = 0.0f, a3 = 0.0f; \
  float b0 = pbB, b1 = 0.0f, b2 = 0.0f, b3 = 0.0f; \
  { const float4* xp_ = (const float4*)(XPTR); \
    _Pragma("unroll") \
    for (int q = 0; q < 16; q++){ float4 xq = xp_[q]; \
      a0 = fmaf(xq.x, wxA[4*q+0], a0); a1 = fmaf(xq.y, wxA[4*q+1], a1); \
      a2 = fmaf(xq.z, wxA[4*q+2], a2); a3 = fmaf(xq.w, wxA[4*q+3], a3); \
      b0 = fmaf(xq.x, wxB[4*q+0], b0); b1 = fmaf(xq.y, wxB[4*q+1], b1); \
      b2 = fmaf(xq.z, wxB[4*q+2], b2); b3 = fmaf(xq.w, wxB[4*q+3], b3); } }

#define L1_HFMA() \
  { const float4* h4_ = (const float4*)hbuf; \
    _Pragma("unroll") \
    for (int q = 0; q < HL/4; q++){ float4 hq = h4_[q]; \
      a0 = fmaf(hq.x, whA[4*q+0], a0); a1 = fmaf(hq.y, whA[4*q+1], a1); \
      a2 = fmaf(hq.z, whA[4*q+2], a2); a3 = fmaf(hq.w, whA[4*q+3], a3); \
      b0 = fmaf(hq.x, whB[4*q+0], b0); b1 = fmaf(hq.y, whB[4*q+1], b1); \
      b2 = fmaf(hq.z, whB[4*q+2], b2); b3 = fmaf(hq.w, whB[4*q+3], b3); } }

#define L1_STORE() \
  c = cn; h = hn; hsum += h; \
  if (!half) hbuf[j] = h;

  if (dir == 0){
    // ---- full phase: t = 0 .. min(tcv, TS-1) ----
    const int tend = (tcv < TS-1) ? tcv : TS-1;
    { float x0 = gin[lane];
      if (mz && 0 >= cnt) x0 = 0.0f;
      xrow[0][lane] = x0; }
    float v1 = gin[64 + lane], v2 = gin[128 + lane], v3 = gin[192 + lane];
    int ph = 0;
    for (int t = 0; t <= tend; t++){
      L1_GATES(xrow[ph]);
      { int tn = t + 1; float xw = (mz && tn >= cnt) ? 0.0f : v1;
        xrow[ph^1][lane] = xw; }                 // row t+1 (load 4 steps old)
      v1 = v2; v2 = v3;
      { int tp = t + 4; if (tp > TS-1) tp = TS-1;
        v3 = gin[(size_t)tp*64 + lane]; }        // issue row t+4, stays in flight
      L1_HFMA();
      LTAIL();
      L1_STORE();
      ph ^= 1;
    }
    // ---- cheap phase: rows >= tcv+1 bitwise equal; xrow[ph] holds row tcv+1 ----
    if (tcv < TS-1){
      float xc0 = pbA, xc1 = 0.0f, xc2 = 0.0f, xc3 = 0.0f;
      float yc0 = pbB, yc1 = 0.0f, yc2 = 0.0f, yc3 = 0.0f;
      { const float4* xp = (const float4*)xrow[ph];
#pragma unroll
        for (int q = 0; q < 16; q++){ float4 xq = xp[q];
          xc0 = fmaf(xq.x, wxA[4*q+0], xc0); xc1 = fmaf(xq.y, wxA[4*q+1], xc1);
          xc2 = fmaf(xq.z, wxA[4*q+2], xc2); xc3 = fmaf(xq.w, wxA[4*q+3], xc3);
          yc0 = fmaf(xq.x, wxB[4*q+0], yc0); yc1 = fmaf(xq.y, wxB[4*q+1], yc1);
          yc2 = fmaf(xq.z, wxB[4*q+2], yc2); yc3 = fmaf(xq.w, wxB[4*q+3], yc3); } }
      for (int t = tcv+1; t < TS; t++){
        float a0 = xc0, a1 = xc1, a2 = xc2, a3 = xc3;
        float b0 = yc0, b1 = yc1, b2 = yc2, b3 = yc3;
        L1_HFMA();
        LTAIL();
        bool eq = (fabsf(cn - c) <= CEPS*(1.0f + fabsf(cn))) && (fabsf(hn - h) <= HEPS);
        L1_STORE();
        unsigned long long m = __ballot(eq);
        if (m == ~0ull){ hsum += h * (float)(TS-1 - t); break; }  // fixed point
      }
    }
  } else {
    // ---- dir 1: cheap phase first (rows TS-1..tcv+1 bitwise equal) ----
    int tfull;
    if (tcv + 1 <= TS - 1){
      { float x0 = gin[(size_t)(tcv+1)*64 + lane];
        if (mz && tcv+1 >= cnt) x0 = 0.0f;
        xrow[0][lane] = x0; }                    // constant row content
      float xc0 = pbA, xc1 = 0.0f, xc2 = 0.0f, xc3 = 0.0f;
      float yc0 = pbB, yc1 = 0.0f, yc2 = 0.0f, yc3 = 0.0f;
      { const float4* xp = (const float4*)xrow[0];
#pragma unroll
        for (int q = 0; q < 16; q++){ float4 xq = xp[q];
          xc0 = fmaf(xq.x, wxA[4*q+0], xc0); xc1 = fmaf(xq.y, wxA[4*q+1], xc1);
          xc2 = fmaf(xq.z, wxA[4*q+2], xc2); xc3 = fmaf(xq.w, wxA[4*q+3], xc3);
          yc0 = fmaf(xq.x, wxB[4*q+0], yc0); yc1 = fmaf(xq.y, wxB[4*q+1], yc1);
          yc2 = fmaf(xq.z, wxB[4*q+2], yc2); yc3 = fmaf(xq.w, wxB[4*q+3], yc3); } }
      int t = TS - 1; bool jumped = false;
      for (; t >= tcv + 1; t--){
        float a0 = xc0, a1 = xc1, a2 = xc2, a3 = xc3;
        float b0 = yc0, b1 = yc1, b2 = yc2, b3 = yc3;
        L1_HFMA();
        LTAIL();
        bool eq = (fabsf(cn - c) <= CEPS*(1.0f + fabsf(cn))) && (fabsf(hn - h) <= HEPS);
        L1_STORE();
        unsigned long long m = __ballot(eq);
        if (m == ~0ull){ hsum += h * (float)(t - tcv); jumped = true; break; }
      }
      tfull = jumped ? (tcv - 1) : tcv;
    } else tfull = TS - 1;
    // ---- full descending phase: t = tfull .. 0 ----
    if (tfull >= 0){
      { float x0 = gin[(size_t)tfull*64 + lane];
        if (mz && tfull >= cnt) x0 = 0.0f;
        xrow[0][lane] = x0; }
      int r1 = tfull-1 < 0 ? 0 : tfull-1;
      int r2 = tfull-2 < 0 ? 0 : tfull-2;
      int r3 = tfull-3 < 0 ? 0 : tfull-3;
      float v1 = gin[(size_t)r1*64 + lane];
      float v2 = gin[(size_t)r2*64 + lane];
      float v3 = gin[(size_t)r3*64 + lane];
      int ph = 0;
      for (int t = tfull; t >= 0; t--){
        L1_GATES(xrow[ph]);
        { int tn = t - 1; float xw = (mz && tn >= cnt) ? 0.0f : v1;
          xrow[ph^1][lane] = xw; }               // row t-1
        v1 = v2; v2 = v3;
        { int tp = t - 4; if (tp < 0) tp = 0;
          v3 = gin[(size_t)tp*64 + lane]; }
        L1_HFMA();
        LTAIL();
        L1_STORE();
        ph ^= 1;
      }
    }
  }
  if (!half) pooled[(size_t)g*64 + dir*32 + j] = hsum * (1.0f/(float)TS);
#undef L1_GATES
#undef L1_HFMA
#undef L1_STORE
}

// ---------------- FC: out = pooled @ fc_w + fc_b ----------------
__global__ void k_fc(const float* __restrict__ pooled, const float* __restrict__ fcw,
                     const float* __restrict__ fcb, float* __restrict__ out){
  __shared__ float p[64];
  int g = blockIdx.x, cix = threadIdx.x;
  if (cix < 64) p[cix] = pooled[(size_t)g*64 + cix];
  __syncthreads();
  float acc = fcb[cix];
#pragma unroll
  for (int k = 0; k < 64; k++) acc = fmaf(p[k], fcw[k*NC + cix], acc);
  out[(size_t)g*NC + cix] = acc;
}

extern "C" void kernel_launch(void* const* d_in, const int* in_sizes, int n_in,
                              void* d_out, int out_size, void* d_ws, size_t ws_size,
                              hipStream_t stream) {
  const float* x        = (const float*)d_in[0];
  const int*   ei       = (const int*)  d_in[1];
  const int*   batch    = (const int*)  d_in[2];
  const float* gcn_w1   = (const float*)d_in[3];
  const float* gcn_b1   = (const float*)d_in[4];
  const float* gcn_w2   = (const float*)d_in[5];
  const float* gcn_b2   = (const float*)d_in[6];
  const float* l0_wih   = (const float*)d_in[7];
  const float* l0_whh   = (const float*)d_in[8];
  const float* l0_bih   = (const float*)d_in[9];
  const float* l0_bhh   = (const float*)d_in[10];
  const float* l1_wih   = (const float*)d_in[11];
  const float* l1_whh   = (const float*)d_in[12];
  const float* l1_bih   = (const float*)d_in[13];
  const float* l1_bhh   = (const float*)d_in[14];
  const float* fc_w     = (const float*)d_in[15];
  const float* fc_b     = (const float*)d_in[16];
  float* out = (float*)d_out;

  // workspace layout (4B units)
  float* ws   = (float*)d_ws;
  float* B0   = ws;                        // NN*16
  float* B1   = B0 + (size_t)NN*HG;        // NN*16
  float* B2   = B1 + (size_t)NN*HG;        // NN*16
  float* dinv = B2 + (size_t)NN*HG;        // NN
  int*   ecnt   = (int*)(dinv + NN);       // NN
  int*   eoff   = ecnt + NN;               // NN
  int*   hist   = eoff + NN;               // NB*WH = 131072
  int*   offs   = hist + NB*WH;            // 131072
  int*   st     = offs + NB*WH;            // NG+1 (occupies old counts+starts slots)
  int*   tconv  = st + 2*NG;               // 512
  int*   bstart = tconv + NG;              // NB+1
  int*   az     = bstart + NB + 4;         // 1 (inside 64-int pad)
  float* pooled = (float*)(bstart + NB + 64);      // 512*64 (64-int pad)
  int*   csr    = (int*)(pooled + (size_t)NG*64);  // NE
  float* out0   = (float*)(csr + (size_t)NE);      // 512*1024*64
  uint2* pair   = (uint2*)out0;                    // NE*2 ints, aliases out0 (dead before lstm0)
  size_t needed = ((size_t)((float*)out0 - ws) + (size_t)NG*TS*64) * sizeof(float);
  if (ws_size < needed) return;  // fail loudly (poisoned d_out) rather than corrupt

  k_bounds<<<NN/256, 256, 0, stream>>>(batch, st);
  k_hist  <<<WH, 256, 0, stream>>>(ei, hist);
  k_scanH <<<1, 1024, 0, stream>>>(hist, offs, bstart);
  k_binB  <<<WH, 256, 0, stream>>>(ei, offs, pair);
  k_binC  <<<NB, 256, 0, stream>>>(pair, bstart, eoff, ecnt, csr, dinv);
  k_lin1  <<<NN/16, 256, 0, stream>>>(x, gcn_w1, B0);
  k_gather<<<(NN*HG)/256, 256, 0, stream>>>(B0, csr, eoff, ecnt, dinv, gcn_b2, 0, B1);
  k_relu_lin<<<(NN*HG)/256, 256, 0, stream>>>(B1, gcn_b1, gcn_w2, B2);
  k_gather<<<(NN*HG)/256, 256, 0, stream>>>(B2, csr, eoff, ecnt, dinv, gcn_b2, 1, B1);
  k_lstm0 <<<NG*2, 64, 0, stream>>>(B1, st, l0_wih, l0_whh, l0_bih, l0_bhh, out0, tconv, az);
  k_lstm1 <<<NG*2, 64, 0, stream>>>(out0, tconv, st, az, l1_wih, l1_whh, l1_bih, l1_bhh, pooled);
  k_fc    <<<NG, NC, 0, stream>>>(pooled, fc_w, fc_b, out);
}